// Round 4
// baseline (693.808 us; speedup 1.0000x reference)
//
#include <hip/hip_runtime.h>
#include <cstdint>
#include <cstddef>

#define N_NODES_C 100000
#define N_EDGES_C 1250000
#define N_PAIRS_C 200000
#define IN_DIM_C 128
#define HID_C 64

// graph-build geometry
#define NB_S 256
#define BSH 9
#define NPB 512
#define NBKT 196
#define SEG_CAP 8192

// ---------------- scan helpers ----------------

#define SCAN_TPB 256
#define SCAN_IPT 4
#define SCAN_ELEMS 1024

__global__ void k_scan_partial(const int* __restrict__ in, int* __restrict__ outp,
                               int* __restrict__ blocksums, int n) {
    __shared__ int sd[SCAN_TPB];
    int tid = threadIdx.x;
    int base = blockIdx.x * SCAN_ELEMS + tid * SCAN_IPT;
    int v[SCAN_IPT]; int s = 0;
    for (int k = 0; k < SCAN_IPT; k++) { int idx = base + k; v[k] = (idx < n) ? in[idx] : 0; s += v[k]; }
    sd[tid] = s;
    __syncthreads();
    for (int off = 1; off < SCAN_TPB; off <<= 1) {
        int t = (tid >= off) ? sd[tid - off] : 0;
        __syncthreads();
        sd[tid] += t;
        __syncthreads();
    }
    int excl = sd[tid] - s;
    for (int k = 0; k < SCAN_IPT; k++) { int idx = base + k; if (idx < n) outp[idx] = excl; excl += v[k]; }
    if (tid == SCAN_TPB - 1) blocksums[blockIdx.x] = sd[tid];
}

__global__ void k_scan_blocks(int* __restrict__ bs, int nb) {
    __shared__ int sd[128];
    int t = threadIdx.x;
    int v = (t < nb) ? bs[t] : 0;
    sd[t] = v;
    __syncthreads();
    for (int off = 1; off < 128; off <<= 1) {
        int u = (t >= off) ? sd[t - off] : 0;
        __syncthreads();
        sd[t] += u;
        __syncthreads();
    }
    if (t < nb) bs[t] = sd[t] - v;
}

__global__ void k_scan_addg(int* __restrict__ arr, const int* __restrict__ bs, int n) {
    int i = blockIdx.x * blockDim.x + threadIdx.x;
    if (i < n) arr[i] += bs[i >> 10];
}

// ---------------- graph build: two-level counting sort ----------------

__global__ __launch_bounds__(256) void k_hist(const int* __restrict__ dst,
                                              int* __restrict__ histT, int e) {
    __shared__ int lh[NBKT];
    int tid = threadIdx.x, k = blockIdx.x;
    if (tid < NBKT) lh[tid] = 0;
    __syncthreads();
    int chunk = (e + NB_S - 1) / NB_S;
    int i0 = k * chunk, i1 = min(i0 + chunk, e);
    for (int i = i0 + tid; i < i1; i += 256) atomicAdd(&lh[dst[i] >> BSH], 1);
    __syncthreads();
    if (tid < NBKT) histT[tid * NB_S + k] = lh[tid];
}

__global__ __launch_bounds__(256) void k_scatter(const int* __restrict__ edges,
                                                 const int* __restrict__ offs,
                                                 int2* __restrict__ staging, int e) {
    __shared__ int cur[NBKT];
    int tid = threadIdx.x, k = blockIdx.x;
    if (tid < NBKT) cur[tid] = offs[tid * NB_S + k];
    __syncthreads();
    int chunk = (e + NB_S - 1) / NB_S;
    int i0 = k * chunk, i1 = min(i0 + chunk, e);
    for (int i = i0 + tid; i < i1; i += 256) {
        int s = edges[i];
        int d = edges[e + i];
        int p = atomicAdd(&cur[d >> BSH], 1);
        staging[p] = make_int2(s, d);
    }
}

__global__ __launch_bounds__(256) void k_bucket_fill(const int2* __restrict__ staging,
        const int* __restrict__ offs, int* __restrict__ rowptr,
        float* __restrict__ invd, int* __restrict__ adj, int n, int e) {
    __shared__ int ldeg[NPB];
    __shared__ int lrow[NPB];
    __shared__ int ps[256];
    __shared__ int lseg[SEG_CAP];
    int tid = threadIdx.x, b = blockIdx.x;
    int n0 = b << BSH;
    int nn = min(NPB, n - n0);
    int segBeg = offs[b * NB_S];
    int segEnd = (b == NBKT - 1) ? e : offs[(b + 1) * NB_S];

    ldeg[tid] = 0; ldeg[tid + 256] = 0;
    __syncthreads();
    for (int i = segBeg + tid; i < segEnd; i += 256)
        atomicAdd(&ldeg[staging[i].y - n0], 1);
    __syncthreads();

    int a0 = ldeg[2 * tid], a1 = ldeg[2 * tid + 1];
    int s = a0 + a1;
    ps[tid] = s;
    __syncthreads();
    for (int off = 1; off < 256; off <<= 1) {
        int t = (tid >= off) ? ps[tid - off] : 0;
        __syncthreads();
        ps[tid] += t;
        __syncthreads();
    }
    int excl = ps[tid] - s;
    lrow[2 * tid] = excl;
    lrow[2 * tid + 1] = excl + a0;
    __syncthreads();

    for (int j = tid; j < nn; j += 256) {
        rowptr[n0 + j] = segBeg + lrow[j];
        int d = ldeg[j];
        invd[n0 + j] = (d > 0) ? (1.0f / (float)d) : 0.0f;
    }
    if (b == NBKT - 1 && tid == 0) rowptr[n] = e;
    __syncthreads();

    for (int i = segBeg + tid; i < segEnd; i += 256) {
        int2 ed = staging[i];
        int p = atomicAdd(&lrow[ed.y - n0], 1);
        if (p < SEG_CAP) lseg[p] = ed.x;
        else adj[segBeg + p] = ed.x;
    }
    __syncthreads();

    int m = segEnd - segBeg; if (m > SEG_CAP) m = SEG_CAP;
    for (int p = tid; p < m; p += 256) adj[segBeg + p] = lseg[p];
}

// ---------------- helpers ----------------

__device__ __forceinline__ float4 ld4(const float* p) { return *(const float4*)p; }

__device__ __forceinline__ void fma4(float4& acc, float sc, const float4& wv) {
    acc.x = fmaf(sc, wv.x, acc.x);
    acc.y = fmaf(sc, wv.y, acc.y);
    acc.z = fmaf(sc, wv.z, acc.z);
    acc.w = fmaf(sc, wv.w, acc.w);
}

// ---------------- k_nn: encoder GEMM (8-row x 4-col thread tile) -------------
// BM=128, BN=64, K=128 as two K=64 chunks restaging AT (32 KB) + Wm (32 KB).
// MODE 0: out = relu(x @ encW + b) (A1 = x, row stride 128). MODE 1 retained
// for reference but no longer launched (layers use the fused k_agg_nn).

template<int MODE>
__global__ __launch_bounds__(256, 2) void k_nn(
    const float* __restrict__ A1, const float* __restrict__ A2,
    const float* __restrict__ Ws1, const float* __restrict__ Ws2,
    const float* __restrict__ bias,
    float* __restrict__ outp, int nrows)
{
    __shared__ float AT[64 * 128];   // per-chunk [k][r^sw], 32 KB
    __shared__ float Wm[128 * 64];   // [k][c], 32 KB
    const int t = threadIdx.x;
    const int g0 = blockIdx.x * 128;

    #pragma unroll
    for (int p = 0; p < 8; ++p) {
        int li = p * 256 + t;          // 0..2047
        int k = li >> 4;               // 0..127
        int c4 = (li & 15) * 4;        // 0..60
        float4 wv;
        if (MODE == 0) wv = ld4(Ws1 + k * 64 + c4);
        else           wv = (k < 64) ? ld4(Ws1 + k * 64 + c4)
                                     : ld4(Ws2 + (k - 64) * 64 + c4);
        *(float4*)&Wm[k * 64 + c4] = wv;
    }

    const int tc = t & 15, tr = t >> 4;
    const int c0 = tc * 4;             // out cols c0..c0+3
    const int r0 = tr * 8;             // out rows r0..r0+7
    float4 acc[8];
    #pragma unroll
    for (int i = 0; i < 8; ++i) acc[i] = make_float4(0.f, 0.f, 0.f, 0.f);

    #pragma unroll
    for (int chunk = 0; chunk < 2; ++chunk) {
        #pragma unroll
        for (int p = 0; p < 8; ++p) {
            int li = p * 256 + t;          // 128 rows x 16 k4-groups
            int r = li >> 4;               // 0..127
            int c4 = (li & 15) * 4;        // 0..60 (k within chunk)
            int g = g0 + r; if (g > nrows - 1) g = nrows - 1;
            float4 av;
            if (MODE == 0) av = ld4(A1 + (size_t)g * 128 + chunk * 64 + c4);
            else           av = (chunk == 0) ? ld4(A1 + (size_t)g * 64 + c4)
                                             : ld4(A2 + (size_t)g * 64 + c4);
            AT[(c4    ) * 128 + (r ^ (((c4    ) >> 2) * 4))] = av.x;
            AT[(c4 + 1) * 128 + (r ^ (((c4 + 1) >> 2) * 4))] = av.y;
            AT[(c4 + 2) * 128 + (r ^ (((c4 + 2) >> 2) * 4))] = av.z;
            AT[(c4 + 3) * 128 + (r ^ (((c4 + 3) >> 2) * 4))] = av.w;
        }
        __syncthreads();

        #pragma unroll 4
        for (int k = 0; k < 64; ++k) {
            const float* arow = &AT[k * 128];
            int sw = (k >> 2) * 4;
            float4 a0 = ld4(arow + ((r0    ) ^ sw));   // rows r0..r0+3
            float4 a1 = ld4(arow + ((r0 + 4) ^ sw));   // rows r0+4..r0+7
            float4 wv = ld4(&Wm[(chunk * 64 + k) * 64 + c0]);
            fma4(acc[0], a0.x, wv); fma4(acc[1], a0.y, wv);
            fma4(acc[2], a0.z, wv); fma4(acc[3], a0.w, wv);
            fma4(acc[4], a1.x, wv); fma4(acc[5], a1.y, wv);
            fma4(acc[6], a1.z, wv); fma4(acc[7], a1.w, wv);
        }
        __syncthreads();
    }

    float4 bv = ld4(bias + c0);
    #pragma unroll
    for (int i = 0; i < 8; ++i) {
        int g = g0 + r0 + i;
        if (g < nrows) {
            float4 o;
            o.x = fmaxf(acc[i].x + bv.x, 0.f);
            o.y = fmaxf(acc[i].y + bv.y, 0.f);
            o.z = fmaxf(acc[i].z + bv.z, 0.f);
            o.w = fmaxf(acc[i].w + bv.w, 0.f);
            *(float4*)&outp[(size_t)g * 64 + c0] = o;
        }
    }
}

// ---------------- k_agg_nn: fused SAGE layer ---------------------------------
// out = relu( mean_agg(h)[128-row tile] @ Wl + h[tile] @ Wr + b ).
// Phase 1: each wave gathers+aggregates 32 nodes (lane = column k) straight
// into the swizzled AT tile (scalar stores, 8-way bank alias — negligible vs
// the ~400-edge gather per wave). Phase 2: chunk-0 GEMM (Wl). Phase 3: restage
// AT from h rows (coalesced) and chunk-1 GEMM (Wr). Rationale: aggregation is
// L2-miss/gather-bound, GEMM is FMA/LDS-bound — fusing lets the 2 co-resident
// blocks per CU overlap complementary phases, and kills the agg buffer
// round-trip (154 MB across 3 layers).

__global__ __launch_bounds__(256, 2) void k_agg_nn(
    const int* __restrict__ rowptr, const int* __restrict__ adj,
    const float* __restrict__ invd, const float* __restrict__ hin,
    const float* __restrict__ Wl, const float* __restrict__ Wr,
    const float* __restrict__ bias,
    float* __restrict__ outp, int nrows)
{
    __shared__ float AT[64 * 128];   // [k][r^sw], 32 KB
    __shared__ float Wm[128 * 64];   // [k][c]: k<64 = Wl, k>=64 = Wr. 32 KB
    const int t = threadIdx.x;
    const int g0 = blockIdx.x * 128;

    #pragma unroll
    for (int p = 0; p < 8; ++p) {
        int li = p * 256 + t;
        int k = li >> 4;
        int c4 = (li & 15) * 4;
        float4 wv = (k < 64) ? ld4(Wl + k * 64 + c4)
                             : ld4(Wr + (k - 64) * 64 + c4);
        *(float4*)&Wm[k * 64 + c4] = wv;
    }

    // phase 1: gather-aggregate into AT. wave wid -> nodes wid*32..wid*32+31.
    const int lane = t & 63;
    const int wid = t >> 6;
    for (int i = 0; i < 32; ++i) {
        int r = wid * 32 + i;
        int g = g0 + r; if (g > nrows - 1) g = nrows - 1;
        int beg = rowptr[g], end = rowptr[g + 1];
        float acc = 0.0f;
        for (int e = beg; e < end; e += 8) {
            int idx[8];
            #pragma unroll
            for (int j = 0; j < 8; ++j) {
                int ee = e + j;
                idx[j] = adj[ee < end ? ee : end - 1];
            }
            float v[8];
            #pragma unroll
            for (int j = 0; j < 8; ++j) v[j] = hin[(size_t)idx[j] * HID_C + lane];
            #pragma unroll
            for (int j = 0; j < 8; ++j) acc += (e + j < end) ? v[j] : 0.0f;
        }
        acc *= invd[g];
        AT[lane * 128 + (r ^ ((lane >> 2) * 4))] = acc;
    }
    __syncthreads();

    // phase 2: chunk-0 GEMM (agg @ Wl)
    const int tc = t & 15, tr = t >> 4;
    const int c0 = tc * 4, r0 = tr * 8;
    float4 acc4[8];
    #pragma unroll
    for (int i = 0; i < 8; ++i) acc4[i] = make_float4(0.f, 0.f, 0.f, 0.f);

    #pragma unroll 4
    for (int k = 0; k < 64; ++k) {
        const float* arow = &AT[k * 128];
        int sw = (k >> 2) * 4;
        float4 a0 = ld4(arow + ((r0    ) ^ sw));
        float4 a1 = ld4(arow + ((r0 + 4) ^ sw));
        float4 wv = ld4(&Wm[k * 64 + c0]);
        fma4(acc4[0], a0.x, wv); fma4(acc4[1], a0.y, wv);
        fma4(acc4[2], a0.z, wv); fma4(acc4[3], a0.w, wv);
        fma4(acc4[4], a1.x, wv); fma4(acc4[5], a1.y, wv);
        fma4(acc4[6], a1.z, wv); fma4(acc4[7], a1.w, wv);
    }
    __syncthreads();

    // phase 3: restage AT from h rows (coalesced), chunk-1 GEMM (h @ Wr)
    #pragma unroll
    for (int p = 0; p < 8; ++p) {
        int li = p * 256 + t;
        int r = li >> 4;
        int c4 = (li & 15) * 4;
        int g = g0 + r; if (g > nrows - 1) g = nrows - 1;
        float4 av = ld4(hin + (size_t)g * 64 + c4);
        AT[(c4    ) * 128 + (r ^ (((c4    ) >> 2) * 4))] = av.x;
        AT[(c4 + 1) * 128 + (r ^ (((c4 + 1) >> 2) * 4))] = av.y;
        AT[(c4 + 2) * 128 + (r ^ (((c4 + 2) >> 2) * 4))] = av.z;
        AT[(c4 + 3) * 128 + (r ^ (((c4 + 3) >> 2) * 4))] = av.w;
    }
    __syncthreads();

    #pragma unroll 4
    for (int k = 0; k < 64; ++k) {
        const float* arow = &AT[k * 128];
        int sw = (k >> 2) * 4;
        float4 a0 = ld4(arow + ((r0    ) ^ sw));
        float4 a1 = ld4(arow + ((r0 + 4) ^ sw));
        float4 wv = ld4(&Wm[(64 + k) * 64 + c0]);
        fma4(acc4[0], a0.x, wv); fma4(acc4[1], a0.y, wv);
        fma4(acc4[2], a0.z, wv); fma4(acc4[3], a0.w, wv);
        fma4(acc4[4], a1.x, wv); fma4(acc4[5], a1.y, wv);
        fma4(acc4[6], a1.z, wv); fma4(acc4[7], a1.w, wv);
    }

    float4 bv = ld4(bias + c0);
    #pragma unroll
    for (int i = 0; i < 8; ++i) {
        int g = g0 + r0 + i;
        if (g < nrows) {
            float4 o;
            o.x = fmaxf(acc4[i].x + bv.x, 0.f);
            o.y = fmaxf(acc4[i].y + bv.y, 0.f);
            o.z = fmaxf(acc4[i].z + bv.z, 0.f);
            o.w = fmaxf(acc4[i].w + bv.w, 0.f);
            *(float4*)&outp[(size_t)g * 64 + c0] = o;
        }
    }
}

// ---------------- pred-path factorization ----------------
// z@W1 = (h@W1[:64])[a] + (h@W1[64:])[b].
// k_uv: UV GEMM, M=100k K=64 N=128 (U cols 0..63, V cols 64..127), 8x8 thread
// tile. K=64 staged once, no K-loop. A stored k-major with XOR swizzle
// sw=(k>>2)*4.

__global__ __launch_bounds__(256, 2) void k_uv(
    const float* __restrict__ H, const float* __restrict__ W1,
    float* __restrict__ U, float* __restrict__ V, int nrows)
{
    __shared__ float AT[64 * 128];   // [k][row^sw], 32 KB
    __shared__ float Wm[64 * 128];   // [k][col],    32 KB
    const int t = threadIdx.x;
    const int g0 = blockIdx.x * 128;

    // stage Wc[k][j]: j<64 -> W1[k][j] (U half), else W1[64+k][j-64] (V half)
    #pragma unroll
    for (int p = 0; p < 8; ++p) {
        int li = p * 256 + t;          // 0..2047
        int k = li >> 5;               // 0..63
        int j4 = (li & 31) * 4;        // 0..124
        float4 wv = (j4 < 64) ? ld4(W1 + k * 64 + j4)
                              : ld4(W1 + (64 + k) * 64 + (j4 - 64));
        *(float4*)&Wm[k * 128 + j4] = wv;
    }
    // stage A transposed + swizzled: AT[k][r ^ ((k>>2)*4)] = H[g0+r][k]
    #pragma unroll
    for (int p = 0; p < 8; ++p) {
        int li = p * 256 + t;          // 128 rows x 16 col4-groups
        int r = li >> 4;               // 0..127
        int c4 = (li & 15) * 4;        // 0..60
        int g = g0 + r; if (g > nrows - 1) g = nrows - 1;
        float4 av = ld4(H + (size_t)g * 64 + c4);
        AT[(c4    ) * 128 + (r ^ (((c4    ) >> 2) * 4))] = av.x;
        AT[(c4 + 1) * 128 + (r ^ (((c4 + 1) >> 2) * 4))] = av.y;
        AT[(c4 + 2) * 128 + (r ^ (((c4 + 2) >> 2) * 4))] = av.z;
        AT[(c4 + 3) * 128 + (r ^ (((c4 + 3) >> 2) * 4))] = av.w;
    }
    __syncthreads();

    const int tc = t & 15, tr = t >> 4;
    const int c0 = tc * 4;             // U cols c0..c0+3, V cols 64+c0..+3
    const int r0 = tr * 8;             // rows r0..r0+7
    float4 accA[8], accB[8];
    #pragma unroll
    for (int i = 0; i < 8; ++i) {
        accA[i] = make_float4(0.f, 0.f, 0.f, 0.f);
        accB[i] = make_float4(0.f, 0.f, 0.f, 0.f);
    }

    #pragma unroll 4
    for (int k = 0; k < 64; ++k) {
        const float* arow = &AT[k * 128];
        int sw = (k >> 2) * 4;
        float4 a0 = ld4(arow + ((r0    ) ^ sw));   // rows r0..r0+3 at this k
        float4 a1 = ld4(arow + ((r0 + 4) ^ sw));   // rows r0+4..r0+7
        float4 w0 = ld4(&Wm[k * 128 + c0]);        // U cols
        float4 w1 = ld4(&Wm[k * 128 + 64 + c0]);   // V cols
        fma4(accA[0], a0.x, w0); fma4(accB[0], a0.x, w1);
        fma4(accA[1], a0.y, w0); fma4(accB[1], a0.y, w1);
        fma4(accA[2], a0.z, w0); fma4(accB[2], a0.z, w1);
        fma4(accA[3], a0.w, w0); fma4(accB[3], a0.w, w1);
        fma4(accA[4], a1.x, w0); fma4(accB[4], a1.x, w1);
        fma4(accA[5], a1.y, w0); fma4(accB[5], a1.y, w1);
        fma4(accA[6], a1.z, w0); fma4(accB[6], a1.z, w1);
        fma4(accA[7], a1.w, w0); fma4(accB[7], a1.w, w1);
    }

    #pragma unroll
    for (int i = 0; i < 8; ++i) {
        int g = g0 + r0 + i;
        if (g < nrows) {
            *(float4*)&U[(size_t)g * 64 + c0] = accA[i];
            *(float4*)&V[(size_t)g * 64 + c0] = accB[i];
        }
    }
}

// k_pred: out[p] = relu(U[a] + V[b] + b1) . W2 + b2 — pure gather-reduce.
// 16 lanes per pair, 256 B coalesced row per gather, shfl-reduce width 16.
__global__ __launch_bounds__(256) void k_pred(
    const float* __restrict__ U, const float* __restrict__ V,
    const int* __restrict__ pidx, const float* __restrict__ b1,
    const float* __restrict__ W2, const float* __restrict__ b2,
    float* __restrict__ outp, int np)
{
    const int t = threadIdx.x;
    const int lg = t & 15;
    const int p = blockIdx.x * 16 + (t >> 4);
    float4 bv = ld4(b1 + lg * 4);
    float4 wv = ld4(W2 + lg * 4);
    if (p >= np) return;
    int2 ab = ((const int2*)pidx)[p];
    float4 u = ld4(U + (size_t)ab.x * 64 + lg * 4);
    float4 v = ld4(V + (size_t)ab.y * 64 + lg * 4);
    float zx = fmaxf(u.x + v.x + bv.x, 0.f);
    float zy = fmaxf(u.y + v.y + bv.y, 0.f);
    float zz = fmaxf(u.z + v.z + bv.z, 0.f);
    float zw = fmaxf(u.w + v.w + bv.w, 0.f);
    float s = zx * wv.x + zy * wv.y + zz * wv.z + zw * wv.w;
    s += __shfl_down(s, 8, 16);
    s += __shfl_down(s, 4, 16);
    s += __shfl_down(s, 2, 16);
    s += __shfl_down(s, 1, 16);
    if (lg == 0) outp[p] = s + b2[0];
}

// ---------------- launch ----------------

extern "C" void kernel_launch(void* const* d_in, const int* in_sizes, int n_in,
                              void* d_out, int out_size, void* d_ws, size_t ws_size,
                              hipStream_t stream) {
    const float* x    = (const float*)d_in[0];
    const int*   edges= (const int*)d_in[1];
    const int*   pair = (const int*)d_in[2];
    const float* encW = (const float*)d_in[3];
    const float* encb = (const float*)d_in[4];
    const float* Wl   = (const float*)d_in[5];
    const float* bl   = (const float*)d_in[6];
    const float* Wr   = (const float*)d_in[7];
    const float* W1   = (const float*)d_in[8];
    const float* b1   = (const float*)d_in[9];
    const float* W2   = (const float*)d_in[10];
    const float* b2   = (const float*)d_in[11];
    float* out = (float*)d_out;

    const int N = N_NODES_C, E = N_EDGES_C, P = N_PAIRS_C;
    const int* dst = edges + E;
    const int M = NBKT * NB_S;

    char* w = (char*)d_ws;
    auto alloc = [&](size_t bytes) { char* p = w; w += (bytes + 255) & ~(size_t)255; return p; };
    int*   rowptr = (int*)alloc((size_t)(N + 1) * 4);
    int*   histT  = (int*)alloc((size_t)M * 4);
    int*   offs   = (int*)alloc((size_t)M * 4);
    int*   bsums  = (int*)alloc(128 * 4);
    float* invd   = (float*)alloc((size_t)N * 4);
    int*   adj    = (int*)alloc((size_t)E * 4);
    float* h0     = (float*)alloc((size_t)N * HID_C * 4);
    float* h1     = (float*)alloc((size_t)N * HID_C * 4);
    float* agg    = (float*)alloc((size_t)N * HID_C * 4);
    int2*  staging= (int2*)agg;

    int nscan = (M + SCAN_ELEMS - 1) / SCAN_ELEMS;

    hipLaunchKernelGGL(k_hist, dim3(NB_S), dim3(256), 0, stream, dst, histT, E);
    hipLaunchKernelGGL(k_scan_partial, dim3(nscan), dim3(SCAN_TPB), 0, stream, histT, offs, bsums, M);
    hipLaunchKernelGGL(k_scan_blocks, dim3(1), dim3(128), 0, stream, bsums, nscan);
    hipLaunchKernelGGL(k_scan_addg, dim3((M + 255) / 256), dim3(256), 0, stream, offs, bsums, M);
    hipLaunchKernelGGL(k_scatter, dim3(NB_S), dim3(256), 0, stream, edges, offs, staging, E);
    hipLaunchKernelGGL(k_bucket_fill, dim3(NBKT), dim3(256), 0, stream, staging, offs, rowptr, invd, adj, N, E);

    const int NB128 = (N + 127) / 128;

    k_nn<0><<<dim3(NB128), dim3(256), 0, stream>>>(
        x, nullptr, encW, nullptr, encb, h0, N);

    float* hc = h0; float* hn = h1;
    for (int l = 0; l < 3; l++) {
        hipLaunchKernelGGL(k_agg_nn, dim3(NB128), dim3(256), 0, stream,
                           rowptr, adj, invd, hc,
                           Wl + (size_t)l * 64 * 64, Wr + (size_t)l * 64 * 64,
                           bl + (size_t)l * 64, hn, N);
        float* tswap = hc; hc = hn; hn = tswap;
    }

    // pred path: UV = h @ [W1_top | W1_bot], then per-pair gather-reduce.
    // U reuses agg (staging long dead), V reuses the retired h buffer (hn).
    float* Ubuf = agg;
    float* Vbuf = hn;
    const int NB_UV = (N + 127) / 128;
    hipLaunchKernelGGL(k_uv, dim3(NB_UV), dim3(256), 0, stream, hc, W1, Ubuf, Vbuf, N);
    hipLaunchKernelGGL(k_pred, dim3((P + 15) / 16), dim3(256), 0, stream,
                       Ubuf, Vbuf, pair, b1, W2, b2, out, P);
}

// Round 5
// 478.960 us; speedup vs baseline: 1.4486x; 1.4486x over previous
//
#include <hip/hip_runtime.h>
#include <cstdint>
#include <cstddef>

#define N_NODES_C 100000
#define N_EDGES_C 1250000
#define N_PAIRS_C 200000
#define IN_DIM_C 128
#define HID_C 64

// graph-build geometry
#define NB_S 256
#define BSH 9
#define NPB 512
#define NBKT 196
#define SEG_CAP 8192

// ---------------- scan helpers ----------------

#define SCAN_TPB 256
#define SCAN_IPT 4
#define SCAN_ELEMS 1024

__global__ void k_scan_partial(const int* __restrict__ in, int* __restrict__ outp,
                               int* __restrict__ blocksums, int n) {
    __shared__ int sd[SCAN_TPB];
    int tid = threadIdx.x;
    int base = blockIdx.x * SCAN_ELEMS + tid * SCAN_IPT;
    int v[SCAN_IPT]; int s = 0;
    for (int k = 0; k < SCAN_IPT; k++) { int idx = base + k; v[k] = (idx < n) ? in[idx] : 0; s += v[k]; }
    sd[tid] = s;
    __syncthreads();
    for (int off = 1; off < SCAN_TPB; off <<= 1) {
        int t = (tid >= off) ? sd[tid - off] : 0;
        __syncthreads();
        sd[tid] += t;
        __syncthreads();
    }
    int excl = sd[tid] - s;
    for (int k = 0; k < SCAN_IPT; k++) { int idx = base + k; if (idx < n) outp[idx] = excl; excl += v[k]; }
    if (tid == SCAN_TPB - 1) blocksums[blockIdx.x] = sd[tid];
}

__global__ void k_scan_blocks(int* __restrict__ bs, int nb) {
    __shared__ int sd[128];
    int t = threadIdx.x;
    int v = (t < nb) ? bs[t] : 0;
    sd[t] = v;
    __syncthreads();
    for (int off = 1; off < 128; off <<= 1) {
        int u = (t >= off) ? sd[t - off] : 0;
        __syncthreads();
        sd[t] += u;
        __syncthreads();
    }
    if (t < nb) bs[t] = sd[t] - v;
}

__global__ void k_scan_addg(int* __restrict__ arr, const int* __restrict__ bs, int n) {
    int i = blockIdx.x * blockDim.x + threadIdx.x;
    if (i < n) arr[i] += bs[i >> 10];
}

// ---------------- graph build: two-level counting sort ----------------

__global__ __launch_bounds__(256) void k_hist(const int* __restrict__ dst,
                                              int* __restrict__ histT, int e) {
    __shared__ int lh[NBKT];
    int tid = threadIdx.x, k = blockIdx.x;
    if (tid < NBKT) lh[tid] = 0;
    __syncthreads();
    int chunk = (e + NB_S - 1) / NB_S;
    int i0 = k * chunk, i1 = min(i0 + chunk, e);
    for (int i = i0 + tid; i < i1; i += 256) atomicAdd(&lh[dst[i] >> BSH], 1);
    __syncthreads();
    if (tid < NBKT) histT[tid * NB_S + k] = lh[tid];
}

__global__ __launch_bounds__(256) void k_scatter(const int* __restrict__ edges,
                                                 const int* __restrict__ offs,
                                                 int2* __restrict__ staging, int e) {
    __shared__ int cur[NBKT];
    int tid = threadIdx.x, k = blockIdx.x;
    if (tid < NBKT) cur[tid] = offs[tid * NB_S + k];
    __syncthreads();
    int chunk = (e + NB_S - 1) / NB_S;
    int i0 = k * chunk, i1 = min(i0 + chunk, e);
    for (int i = i0 + tid; i < i1; i += 256) {
        int s = edges[i];
        int d = edges[e + i];
        int p = atomicAdd(&cur[d >> BSH], 1);
        staging[p] = make_int2(s, d);
    }
}

__global__ __launch_bounds__(256) void k_bucket_fill(const int2* __restrict__ staging,
        const int* __restrict__ offs, int* __restrict__ rowptr,
        float* __restrict__ invd, int* __restrict__ adj, int n, int e) {
    __shared__ int ldeg[NPB];
    __shared__ int lrow[NPB];
    __shared__ int ps[256];
    __shared__ int lseg[SEG_CAP];
    int tid = threadIdx.x, b = blockIdx.x;
    int n0 = b << BSH;
    int nn = min(NPB, n - n0);
    int segBeg = offs[b * NB_S];
    int segEnd = (b == NBKT - 1) ? e : offs[(b + 1) * NB_S];

    ldeg[tid] = 0; ldeg[tid + 256] = 0;
    __syncthreads();
    for (int i = segBeg + tid; i < segEnd; i += 256)
        atomicAdd(&ldeg[staging[i].y - n0], 1);
    __syncthreads();

    int a0 = ldeg[2 * tid], a1 = ldeg[2 * tid + 1];
    int s = a0 + a1;
    ps[tid] = s;
    __syncthreads();
    for (int off = 1; off < 256; off <<= 1) {
        int t = (tid >= off) ? ps[tid - off] : 0;
        __syncthreads();
        ps[tid] += t;
        __syncthreads();
    }
    int excl = ps[tid] - s;
    lrow[2 * tid] = excl;
    lrow[2 * tid + 1] = excl + a0;
    __syncthreads();

    for (int j = tid; j < nn; j += 256) {
        rowptr[n0 + j] = segBeg + lrow[j];
        int d = ldeg[j];
        invd[n0 + j] = (d > 0) ? (1.0f / (float)d) : 0.0f;
    }
    if (b == NBKT - 1 && tid == 0) rowptr[n] = e;
    __syncthreads();

    for (int i = segBeg + tid; i < segEnd; i += 256) {
        int2 ed = staging[i];
        int p = atomicAdd(&lrow[ed.y - n0], 1);
        if (p < SEG_CAP) lseg[p] = ed.x;
        else adj[segBeg + p] = ed.x;
    }
    __syncthreads();

    int m = segEnd - segBeg; if (m > SEG_CAP) m = SEG_CAP;
    for (int p = tid; p < m; p += 256) adj[segBeg + p] = lseg[p];
}

// ---------------- helpers ----------------

__device__ __forceinline__ float4 ld4(const float* p) { return *(const float4*)p; }

__device__ __forceinline__ void fma4(float4& acc, float sc, const float4& wv) {
    acc.x = fmaf(sc, wv.x, acc.x);
    acc.y = fmaf(sc, wv.y, acc.y);
    acc.z = fmaf(sc, wv.z, acc.z);
    acc.w = fmaf(sc, wv.w, acc.w);
}

// ---------------- aggregation ----------------
// One wave per node (high occupancy — the gather is concurrency-bound; R4
// proved throughput scales with resident waves, so NO fusion into low-occ
// GEMMs). float4 lanes + edge-parallel quarters: each 16-lane quarter loads
// the full 64-col row as float4 (256 B coalesced) for a DIFFERENT edge of the
// same node — 4 edges per wave-instruction, no divergence (shared degree
// loop). Per 8 edges per lane: 2 loads + 8 adds (was 8 loads + 8 adds).
// Cross-quarter reduce: shfl_xor ^16, ^32; quarter 0 writes.

__global__ __launch_bounds__(256) void k_aggregate(const int* __restrict__ rowptr,
        const int* __restrict__ adj, const float* __restrict__ invd,
        const float* __restrict__ hin, float* __restrict__ agg, int n) {
    int wid = threadIdx.x >> 6, lane = threadIdx.x & 63;
    int node = blockIdx.x * 4 + wid;
    if (node >= n) return;
    const int q = lane >> 4;          // quarter 0..3 -> edge slot
    const int c4 = (lane & 15) * 4;   // columns c4..c4+3
    int beg = rowptr[node], end = rowptr[node + 1];
    float4 acc = make_float4(0.f, 0.f, 0.f, 0.f);
    for (int e = beg; e < end; e += 8) {
        int e0 = e + q * 2;
        int e1 = e0 + 1;
        int i0 = adj[e0 < end ? e0 : end - 1];
        int i1 = adj[e1 < end ? e1 : end - 1];
        float4 v0 = ld4(hin + (size_t)i0 * HID_C + c4);
        float4 v1 = ld4(hin + (size_t)i1 * HID_C + c4);
        if (e0 < end) { acc.x += v0.x; acc.y += v0.y; acc.z += v0.z; acc.w += v0.w; }
        if (e1 < end) { acc.x += v1.x; acc.y += v1.y; acc.z += v1.z; acc.w += v1.w; }
    }
    // reduce the 4 quarters (lanes ^16 then ^32 hold the other edge slots)
    acc.x += __shfl_xor(acc.x, 16, 64);
    acc.y += __shfl_xor(acc.y, 16, 64);
    acc.z += __shfl_xor(acc.z, 16, 64);
    acc.w += __shfl_xor(acc.w, 16, 64);
    acc.x += __shfl_xor(acc.x, 32, 64);
    acc.y += __shfl_xor(acc.y, 32, 64);
    acc.z += __shfl_xor(acc.z, 32, 64);
    acc.w += __shfl_xor(acc.w, 32, 64);
    if (q == 0) {
        float s = invd[node];
        float4 o;
        o.x = acc.x * s; o.y = acc.y * s; o.z = acc.z * s; o.w = acc.w * s;
        *(float4*)&agg[(size_t)node * HID_C + c4] = o;
    }
}

// ---------------- k_nn: enc/layer GEMM (8-row x 4-col thread tile) -----------
// BM=128, BN=64, K=128 as two K=64 chunks restaging AT (32 KB) + Wm (32 KB).
// XOR swizzle sw=(k>>2)*4 (production-verified in k_uv).
// MODE 0: out = relu(x @ encW + b)            (A1 = x, row stride 128)
// MODE 1: out = relu(agg @ Ws1 + h @ Ws2 + b) (A1 = agg, A2 = h, stride 64)

template<int MODE>
__global__ __launch_bounds__(256, 2) void k_nn(
    const float* __restrict__ A1, const float* __restrict__ A2,
    const float* __restrict__ Ws1, const float* __restrict__ Ws2,
    const float* __restrict__ bias,
    float* __restrict__ outp, int nrows)
{
    __shared__ float AT[64 * 128];   // per-chunk [k][r^sw], 32 KB
    __shared__ float Wm[128 * 64];   // [k][c], 32 KB
    const int t = threadIdx.x;
    const int g0 = blockIdx.x * 128;

    #pragma unroll
    for (int p = 0; p < 8; ++p) {
        int li = p * 256 + t;          // 0..2047
        int k = li >> 4;               // 0..127
        int c4 = (li & 15) * 4;        // 0..60
        float4 wv;
        if (MODE == 0) wv = ld4(Ws1 + k * 64 + c4);
        else           wv = (k < 64) ? ld4(Ws1 + k * 64 + c4)
                                     : ld4(Ws2 + (k - 64) * 64 + c4);
        *(float4*)&Wm[k * 64 + c4] = wv;
    }

    const int tc = t & 15, tr = t >> 4;
    const int c0 = tc * 4;             // out cols c0..c0+3
    const int r0 = tr * 8;             // out rows r0..r0+7
    float4 acc[8];
    #pragma unroll
    for (int i = 0; i < 8; ++i) acc[i] = make_float4(0.f, 0.f, 0.f, 0.f);

    #pragma unroll
    for (int chunk = 0; chunk < 2; ++chunk) {
        #pragma unroll
        for (int p = 0; p < 8; ++p) {
            int li = p * 256 + t;          // 128 rows x 16 k4-groups
            int r = li >> 4;               // 0..127
            int c4 = (li & 15) * 4;        // 0..60 (k within chunk)
            int g = g0 + r; if (g > nrows - 1) g = nrows - 1;
            float4 av;
            if (MODE == 0) av = ld4(A1 + (size_t)g * 128 + chunk * 64 + c4);
            else           av = (chunk == 0) ? ld4(A1 + (size_t)g * 64 + c4)
                                             : ld4(A2 + (size_t)g * 64 + c4);
            AT[(c4    ) * 128 + (r ^ (((c4    ) >> 2) * 4))] = av.x;
            AT[(c4 + 1) * 128 + (r ^ (((c4 + 1) >> 2) * 4))] = av.y;
            AT[(c4 + 2) * 128 + (r ^ (((c4 + 2) >> 2) * 4))] = av.z;
            AT[(c4 + 3) * 128 + (r ^ (((c4 + 3) >> 2) * 4))] = av.w;
        }
        __syncthreads();

        #pragma unroll 4
        for (int k = 0; k < 64; ++k) {
            const float* arow = &AT[k * 128];
            int sw = (k >> 2) * 4;
            float4 a0 = ld4(arow + ((r0    ) ^ sw));   // rows r0..r0+3
            float4 a1 = ld4(arow + ((r0 + 4) ^ sw));   // rows r0+4..r0+7
            float4 wv = ld4(&Wm[(chunk * 64 + k) * 64 + c0]);
            fma4(acc[0], a0.x, wv); fma4(acc[1], a0.y, wv);
            fma4(acc[2], a0.z, wv); fma4(acc[3], a0.w, wv);
            fma4(acc[4], a1.x, wv); fma4(acc[5], a1.y, wv);
            fma4(acc[6], a1.z, wv); fma4(acc[7], a1.w, wv);
        }
        __syncthreads();
    }

    float4 bv = ld4(bias + c0);
    #pragma unroll
    for (int i = 0; i < 8; ++i) {
        int g = g0 + r0 + i;
        if (g < nrows) {
            float4 o;
            o.x = fmaxf(acc[i].x + bv.x, 0.f);
            o.y = fmaxf(acc[i].y + bv.y, 0.f);
            o.z = fmaxf(acc[i].z + bv.z, 0.f);
            o.w = fmaxf(acc[i].w + bv.w, 0.f);
            *(float4*)&outp[(size_t)g * 64 + c0] = o;
        }
    }
}

// ---------------- pred-path factorization ----------------
// z@W1 = (h@W1[:64])[a] + (h@W1[64:])[b].
// k_uv: UV GEMM, M=100k K=64 N=128 (U cols 0..63, V cols 64..127), 8x8 thread
// tile. K=64 staged once, no K-loop. A stored k-major with XOR swizzle
// sw=(k>>2)*4.

__global__ __launch_bounds__(256, 2) void k_uv(
    const float* __restrict__ H, const float* __restrict__ W1,
    float* __restrict__ U, float* __restrict__ V, int nrows)
{
    __shared__ float AT[64 * 128];   // [k][row^sw], 32 KB
    __shared__ float Wm[64 * 128];   // [k][col],    32 KB
    const int t = threadIdx.x;
    const int g0 = blockIdx.x * 128;

    // stage Wc[k][j]: j<64 -> W1[k][j] (U half), else W1[64+k][j-64] (V half)
    #pragma unroll
    for (int p = 0; p < 8; ++p) {
        int li = p * 256 + t;          // 0..2047
        int k = li >> 5;               // 0..63
        int j4 = (li & 31) * 4;        // 0..124
        float4 wv = (j4 < 64) ? ld4(W1 + k * 64 + j4)
                              : ld4(W1 + (64 + k) * 64 + (j4 - 64));
        *(float4*)&Wm[k * 128 + j4] = wv;
    }
    // stage A transposed + swizzled: AT[k][r ^ ((k>>2)*4)] = H[g0+r][k]
    #pragma unroll
    for (int p = 0; p < 8; ++p) {
        int li = p * 256 + t;          // 128 rows x 16 col4-groups
        int r = li >> 4;               // 0..127
        int c4 = (li & 15) * 4;        // 0..60
        int g = g0 + r; if (g > nrows - 1) g = nrows - 1;
        float4 av = ld4(H + (size_t)g * 64 + c4);
        AT[(c4    ) * 128 + (r ^ (((c4    ) >> 2) * 4))] = av.x;
        AT[(c4 + 1) * 128 + (r ^ (((c4 + 1) >> 2) * 4))] = av.y;
        AT[(c4 + 2) * 128 + (r ^ (((c4 + 2) >> 2) * 4))] = av.z;
        AT[(c4 + 3) * 128 + (r ^ (((c4 + 3) >> 2) * 4))] = av.w;
    }
    __syncthreads();

    const int tc = t & 15, tr = t >> 4;
    const int c0 = tc * 4;             // U cols c0..c0+3, V cols 64+c0..+3
    const int r0 = tr * 8;             // rows r0..r0+7
    float4 accA[8], accB[8];
    #pragma unroll
    for (int i = 0; i < 8; ++i) {
        accA[i] = make_float4(0.f, 0.f, 0.f, 0.f);
        accB[i] = make_float4(0.f, 0.f, 0.f, 0.f);
    }

    #pragma unroll 4
    for (int k = 0; k < 64; ++k) {
        const float* arow = &AT[k * 128];
        int sw = (k >> 2) * 4;
        float4 a0 = ld4(arow + ((r0    ) ^ sw));   // rows r0..r0+3 at this k
        float4 a1 = ld4(arow + ((r0 + 4) ^ sw));   // rows r0+4..r0+7
        float4 w0 = ld4(&Wm[k * 128 + c0]);        // U cols
        float4 w1 = ld4(&Wm[k * 128 + 64 + c0]);   // V cols
        fma4(accA[0], a0.x, w0); fma4(accB[0], a0.x, w1);
        fma4(accA[1], a0.y, w0); fma4(accB[1], a0.y, w1);
        fma4(accA[2], a0.z, w0); fma4(accB[2], a0.z, w1);
        fma4(accA[3], a0.w, w0); fma4(accB[3], a0.w, w1);
        fma4(accA[4], a1.x, w0); fma4(accB[4], a1.x, w1);
        fma4(accA[5], a1.y, w0); fma4(accB[5], a1.y, w1);
        fma4(accA[6], a1.z, w0); fma4(accB[6], a1.z, w1);
        fma4(accA[7], a1.w, w0); fma4(accB[7], a1.w, w1);
    }

    #pragma unroll
    for (int i = 0; i < 8; ++i) {
        int g = g0 + r0 + i;
        if (g < nrows) {
            *(float4*)&U[(size_t)g * 64 + c0] = accA[i];
            *(float4*)&V[(size_t)g * 64 + c0] = accB[i];
        }
    }
}

// k_pred: out[p] = relu(U[a] + V[b] + b1) . W2 + b2 — pure gather-reduce.
// 16 lanes per pair, 256 B coalesced row per gather, shfl-reduce width 16.
__global__ __launch_bounds__(256) void k_pred(
    const float* __restrict__ U, const float* __restrict__ V,
    const int* __restrict__ pidx, const float* __restrict__ b1,
    const float* __restrict__ W2, const float* __restrict__ b2,
    float* __restrict__ outp, int np)
{
    const int t = threadIdx.x;
    const int lg = t & 15;
    const int p = blockIdx.x * 16 + (t >> 4);
    float4 bv = ld4(b1 + lg * 4);
    float4 wv = ld4(W2 + lg * 4);
    if (p >= np) return;
    int2 ab = ((const int2*)pidx)[p];
    float4 u = ld4(U + (size_t)ab.x * 64 + lg * 4);
    float4 v = ld4(V + (size_t)ab.y * 64 + lg * 4);
    float zx = fmaxf(u.x + v.x + bv.x, 0.f);
    float zy = fmaxf(u.y + v.y + bv.y, 0.f);
    float zz = fmaxf(u.z + v.z + bv.z, 0.f);
    float zw = fmaxf(u.w + v.w + bv.w, 0.f);
    float s = zx * wv.x + zy * wv.y + zz * wv.z + zw * wv.w;
    s += __shfl_down(s, 8, 16);
    s += __shfl_down(s, 4, 16);
    s += __shfl_down(s, 2, 16);
    s += __shfl_down(s, 1, 16);
    if (lg == 0) outp[p] = s + b2[0];
}

// ---------------- launch ----------------

extern "C" void kernel_launch(void* const* d_in, const int* in_sizes, int n_in,
                              void* d_out, int out_size, void* d_ws, size_t ws_size,
                              hipStream_t stream) {
    const float* x    = (const float*)d_in[0];
    const int*   edges= (const int*)d_in[1];
    const int*   pair = (const int*)d_in[2];
    const float* encW = (const float*)d_in[3];
    const float* encb = (const float*)d_in[4];
    const float* Wl   = (const float*)d_in[5];
    const float* bl   = (const float*)d_in[6];
    const float* Wr   = (const float*)d_in[7];
    const float* W1   = (const float*)d_in[8];
    const float* b1   = (const float*)d_in[9];
    const float* W2   = (const float*)d_in[10];
    const float* b2   = (const float*)d_in[11];
    float* out = (float*)d_out;

    const int N = N_NODES_C, E = N_EDGES_C, P = N_PAIRS_C;
    const int* dst = edges + E;
    const int M = NBKT * NB_S;

    char* w = (char*)d_ws;
    auto alloc = [&](size_t bytes) { char* p = w; w += (bytes + 255) & ~(size_t)255; return p; };
    int*   rowptr = (int*)alloc((size_t)(N + 1) * 4);
    int*   histT  = (int*)alloc((size_t)M * 4);
    int*   offs   = (int*)alloc((size_t)M * 4);
    int*   bsums  = (int*)alloc(128 * 4);
    float* invd   = (float*)alloc((size_t)N * 4);
    int*   adj    = (int*)alloc((size_t)E * 4);
    float* h0     = (float*)alloc((size_t)N * HID_C * 4);
    float* h1     = (float*)alloc((size_t)N * HID_C * 4);
    float* agg    = (float*)alloc((size_t)N * HID_C * 4);
    int2*  staging= (int2*)agg;

    int nscan = (M + SCAN_ELEMS - 1) / SCAN_ELEMS;

    hipLaunchKernelGGL(k_hist, dim3(NB_S), dim3(256), 0, stream, dst, histT, E);
    hipLaunchKernelGGL(k_scan_partial, dim3(nscan), dim3(SCAN_TPB), 0, stream, histT, offs, bsums, M);
    hipLaunchKernelGGL(k_scan_blocks, dim3(1), dim3(128), 0, stream, bsums, nscan);
    hipLaunchKernelGGL(k_scan_addg, dim3((M + 255) / 256), dim3(256), 0, stream, offs, bsums, M);
    hipLaunchKernelGGL(k_scatter, dim3(NB_S), dim3(256), 0, stream, edges, offs, staging, E);
    hipLaunchKernelGGL(k_bucket_fill, dim3(NBKT), dim3(256), 0, stream, staging, offs, rowptr, invd, adj, N, E);

    const int NB128 = (N + 127) / 128;

    k_nn<0><<<dim3(NB128), dim3(256), 0, stream>>>(
        x, nullptr, encW, nullptr, encb, h0, N);

    float* hc = h0; float* hn = h1;
    for (int l = 0; l < 3; l++) {
        hipLaunchKernelGGL(k_aggregate, dim3((N + 3) / 4), dim3(256), 0, stream,
                           rowptr, adj, invd, hc, agg, N);
        k_nn<1><<<dim3(NB128), dim3(256), 0, stream>>>(
            agg, hc, Wl + (size_t)l * 64 * 64, Wr + (size_t)l * 64 * 64,
            bl + (size_t)l * 64, hn, N);
        float* tswap = hc; hc = hn; hn = tswap;
    }

    // pred path: UV = h @ [W1_top | W1_bot], then per-pair gather-reduce.
    // U reuses agg (staging long dead), V reuses the retired h buffer (hn).
    float* Ubuf = agg;
    float* Vbuf = hn;
    const int NB_UV = (N + 127) / 128;
    hipLaunchKernelGGL(k_uv, dim3(NB_UV), dim3(256), 0, stream, hc, W1, Ubuf, Vbuf, N);
    hipLaunchKernelGGL(k_pred, dim3((P + 15) / 16), dim3(256), 0, stream,
                       Ubuf, Vbuf, pair, b1, W2, b2, out, P);
}

// Round 6
// 461.993 us; speedup vs baseline: 1.5018x; 1.0367x over previous
//
#include <hip/hip_runtime.h>
#include <cstdint>
#include <cstddef>

#define N_NODES_C 100000
#define N_EDGES_C 1250000
#define N_PAIRS_C 200000
#define IN_DIM_C 128
#define HID_C 64

// graph-build geometry
#define NB_S 256
#define BSH 9
#define NPB 512
#define NBKT 196
#define SEG_CAP 8192

// ---------------- scan helpers ----------------

#define SCAN_TPB 256
#define SCAN_IPT 4
#define SCAN_ELEMS 1024

__global__ void k_scan_partial(const int* __restrict__ in, int* __restrict__ outp,
                               int* __restrict__ blocksums, int n) {
    __shared__ int sd[SCAN_TPB];
    int tid = threadIdx.x;
    int base = blockIdx.x * SCAN_ELEMS + tid * SCAN_IPT;
    int v[SCAN_IPT]; int s = 0;
    for (int k = 0; k < SCAN_IPT; k++) { int idx = base + k; v[k] = (idx < n) ? in[idx] : 0; s += v[k]; }
    sd[tid] = s;
    __syncthreads();
    for (int off = 1; off < SCAN_TPB; off <<= 1) {
        int t = (tid >= off) ? sd[tid - off] : 0;
        __syncthreads();
        sd[tid] += t;
        __syncthreads();
    }
    int excl = sd[tid] - s;
    for (int k = 0; k < SCAN_IPT; k++) { int idx = base + k; if (idx < n) outp[idx] = excl; excl += v[k]; }
    if (tid == SCAN_TPB - 1) blocksums[blockIdx.x] = sd[tid];
}

__global__ void k_scan_blocks(int* __restrict__ bs, int nb) {
    __shared__ int sd[128];
    int t = threadIdx.x;
    int v = (t < nb) ? bs[t] : 0;
    sd[t] = v;
    __syncthreads();
    for (int off = 1; off < 128; off <<= 1) {
        int u = (t >= off) ? sd[t - off] : 0;
        __syncthreads();
        sd[t] += u;
        __syncthreads();
    }
    if (t < nb) bs[t] = sd[t] - v;
}

__global__ void k_scan_addg(int* __restrict__ arr, const int* __restrict__ bs, int n) {
    int i = blockIdx.x * blockDim.x + threadIdx.x;
    if (i < n) arr[i] += bs[i >> 10];
}

// ---------------- graph build: two-level counting sort ----------------

__global__ __launch_bounds__(256) void k_hist(const int* __restrict__ dst,
                                              int* __restrict__ histT, int e) {
    __shared__ int lh[NBKT];
    int tid = threadIdx.x, k = blockIdx.x;
    if (tid < NBKT) lh[tid] = 0;
    __syncthreads();
    int chunk = (e + NB_S - 1) / NB_S;
    int i0 = k * chunk, i1 = min(i0 + chunk, e);
    for (int i = i0 + tid; i < i1; i += 256) atomicAdd(&lh[dst[i] >> BSH], 1);
    __syncthreads();
    if (tid < NBKT) histT[tid * NB_S + k] = lh[tid];
}

__global__ __launch_bounds__(256) void k_scatter(const int* __restrict__ edges,
                                                 const int* __restrict__ offs,
                                                 int2* __restrict__ staging, int e) {
    __shared__ int cur[NBKT];
    int tid = threadIdx.x, k = blockIdx.x;
    if (tid < NBKT) cur[tid] = offs[tid * NB_S + k];
    __syncthreads();
    int chunk = (e + NB_S - 1) / NB_S;
    int i0 = k * chunk, i1 = min(i0 + chunk, e);
    for (int i = i0 + tid; i < i1; i += 256) {
        int s = edges[i];
        int d = edges[e + i];
        int p = atomicAdd(&cur[d >> BSH], 1);
        staging[p] = make_int2(s, d);
    }
}

__global__ __launch_bounds__(256) void k_bucket_fill(const int2* __restrict__ staging,
        const int* __restrict__ offs, int* __restrict__ rowptr,
        float* __restrict__ invd, int* __restrict__ adj, int n, int e) {
    __shared__ int ldeg[NPB];
    __shared__ int lrow[NPB];
    __shared__ int ps[256];
    __shared__ int lseg[SEG_CAP];
    int tid = threadIdx.x, b = blockIdx.x;
    int n0 = b << BSH;
    int nn = min(NPB, n - n0);
    int segBeg = offs[b * NB_S];
    int segEnd = (b == NBKT - 1) ? e : offs[(b + 1) * NB_S];

    ldeg[tid] = 0; ldeg[tid + 256] = 0;
    __syncthreads();
    for (int i = segBeg + tid; i < segEnd; i += 256)
        atomicAdd(&ldeg[staging[i].y - n0], 1);
    __syncthreads();

    int a0 = ldeg[2 * tid], a1 = ldeg[2 * tid + 1];
    int s = a0 + a1;
    ps[tid] = s;
    __syncthreads();
    for (int off = 1; off < 256; off <<= 1) {
        int t = (tid >= off) ? ps[tid - off] : 0;
        __syncthreads();
        ps[tid] += t;
        __syncthreads();
    }
    int excl = ps[tid] - s;
    lrow[2 * tid] = excl;
    lrow[2 * tid + 1] = excl + a0;
    __syncthreads();

    for (int j = tid; j < nn; j += 256) {
        rowptr[n0 + j] = segBeg + lrow[j];
        int d = ldeg[j];
        invd[n0 + j] = (d > 0) ? (1.0f / (float)d) : 0.0f;
    }
    if (b == NBKT - 1 && tid == 0) rowptr[n] = e;
    __syncthreads();

    for (int i = segBeg + tid; i < segEnd; i += 256) {
        int2 ed = staging[i];
        int p = atomicAdd(&lrow[ed.y - n0], 1);
        if (p < SEG_CAP) lseg[p] = ed.x;
        else adj[segBeg + p] = ed.x;
    }
    __syncthreads();

    int m = segEnd - segBeg; if (m > SEG_CAP) m = SEG_CAP;
    for (int p = tid; p < m; p += 256) adj[segBeg + p] = lseg[p];
}

// ---------------- aggregation ----------------
// R2/R3 PROVEN FORM (51.5 us) — reinstated after two falsified reworks:
// R4 fusion (164 us: gather is concurrency-bound, low-occ fusion strangles it)
// and R5 float4/edge-parallel (54.5 us: VALU cut 2x, no gain — memory-system
// bound at ~5.9 TB/s delivered / 3.1 TB/s past-L2 for random 256 B rows).
// Do not shave instructions here; only fewer-bytes changes can help.

__global__ __launch_bounds__(256) void k_aggregate(const int* __restrict__ rowptr,
        const int* __restrict__ adj, const float* __restrict__ invd,
        const float* __restrict__ hin, float* __restrict__ agg, int n) {
    int wid = threadIdx.x >> 6, lane = threadIdx.x & 63;
    int node = blockIdx.x * 4 + wid;
    if (node >= n) return;
    int beg = rowptr[node], end = rowptr[node + 1];
    float acc = 0.0f;
    for (int e = beg; e < end; e += 8) {
        int idx[8];
        #pragma unroll
        for (int j = 0; j < 8; ++j) {
            int ee = e + j;
            idx[j] = adj[ee < end ? ee : end - 1];
        }
        float v[8];
        #pragma unroll
        for (int j = 0; j < 8; ++j) v[j] = hin[(size_t)idx[j] * HID_C + lane];
        #pragma unroll
        for (int j = 0; j < 8; ++j) acc += (e + j < end) ? v[j] : 0.0f;
    }
    agg[(size_t)node * HID_C + lane] = acc * invd[node];
}

// ---------------- helpers ----------------

__device__ __forceinline__ float4 ld4(const float* p) { return *(const float4*)p; }

__device__ __forceinline__ void fma4(float4& acc, float sc, const float4& wv) {
    acc.x = fmaf(sc, wv.x, acc.x);
    acc.y = fmaf(sc, wv.y, acc.y);
    acc.z = fmaf(sc, wv.z, acc.z);
    acc.w = fmaf(sc, wv.w, acc.w);
}

// ---------------- k_nn: enc/layer GEMM (8-row x 4-col thread tile) -----------
// BM=128, BN=64, K=128 as two K=64 chunks. LDS DIET (this round's change):
// Wm is staged PER CHUNK (16 KB) instead of holding both chunks (32 KB) —
// AT 32 KB + Wm 16 KB = 48 KB -> 3 blocks/CU (was 2), +50% resident waves to
// hide ds_read latency. Inner loop unchanged. XOR swizzle sw=(k>>2)*4.
// MODE 0: out = relu(x @ encW + b)            (A1 = x, row stride 128)
// MODE 1: out = relu(agg @ Ws1 + h @ Ws2 + b) (A1 = agg, A2 = h, stride 64)

template<int MODE>
__global__ __launch_bounds__(256, 2) void k_nn(
    const float* __restrict__ A1, const float* __restrict__ A2,
    const float* __restrict__ Ws1, const float* __restrict__ Ws2,
    const float* __restrict__ bias,
    float* __restrict__ outp, int nrows)
{
    __shared__ float AT[64 * 128];   // per-chunk [k][r^sw], 32 KB
    __shared__ float Wm[64 * 64];    // per-chunk [k][c],    16 KB
    const int t = threadIdx.x;
    const int g0 = blockIdx.x * 128;

    const int tc = t & 15, tr = t >> 4;
    const int c0 = tc * 4;             // out cols c0..c0+3
    const int r0 = tr * 8;             // out rows r0..r0+7
    float4 acc[8];
    #pragma unroll
    for (int i = 0; i < 8; ++i) acc[i] = make_float4(0.f, 0.f, 0.f, 0.f);

    #pragma unroll
    for (int chunk = 0; chunk < 2; ++chunk) {
        // stage Wm for this chunk: 64x64 = 1024 float4
        #pragma unroll
        for (int p = 0; p < 4; ++p) {
            int li = p * 256 + t;          // 0..1023
            int k = li >> 4;               // 0..63
            int c4 = (li & 15) * 4;        // 0..60
            const float* wsrc;
            if (MODE == 0) wsrc = Ws1 + (chunk * 64 + k) * 64 + c4;
            else           wsrc = (chunk == 0) ? (Ws1 + k * 64 + c4)
                                               : (Ws2 + k * 64 + c4);
            *(float4*)&Wm[k * 64 + c4] = ld4(wsrc);
        }
        // stage AT[k][r ^ ((k>>2)*4)] for this K-chunk
        #pragma unroll
        for (int p = 0; p < 8; ++p) {
            int li = p * 256 + t;          // 128 rows x 16 k4-groups
            int r = li >> 4;               // 0..127
            int c4 = (li & 15) * 4;        // 0..60 (k within chunk)
            int g = g0 + r; if (g > nrows - 1) g = nrows - 1;
            float4 av;
            if (MODE == 0) av = ld4(A1 + (size_t)g * 128 + chunk * 64 + c4);
            else           av = (chunk == 0) ? ld4(A1 + (size_t)g * 64 + c4)
                                             : ld4(A2 + (size_t)g * 64 + c4);
            AT[(c4    ) * 128 + (r ^ (((c4    ) >> 2) * 4))] = av.x;
            AT[(c4 + 1) * 128 + (r ^ (((c4 + 1) >> 2) * 4))] = av.y;
            AT[(c4 + 2) * 128 + (r ^ (((c4 + 2) >> 2) * 4))] = av.z;
            AT[(c4 + 3) * 128 + (r ^ (((c4 + 3) >> 2) * 4))] = av.w;
        }
        __syncthreads();

        #pragma unroll 4
        for (int k = 0; k < 64; ++k) {
            const float* arow = &AT[k * 128];
            int sw = (k >> 2) * 4;
            float4 a0 = ld4(arow + ((r0    ) ^ sw));   // rows r0..r0+3
            float4 a1 = ld4(arow + ((r0 + 4) ^ sw));   // rows r0+4..r0+7
            float4 wv = ld4(&Wm[k * 64 + c0]);
            fma4(acc[0], a0.x, wv); fma4(acc[1], a0.y, wv);
            fma4(acc[2], a0.z, wv); fma4(acc[3], a0.w, wv);
            fma4(acc[4], a1.x, wv); fma4(acc[5], a1.y, wv);
            fma4(acc[6], a1.z, wv); fma4(acc[7], a1.w, wv);
        }
        __syncthreads();   // protect AT/Wm before restage
    }

    float4 bv = ld4(bias + c0);
    #pragma unroll
    for (int i = 0; i < 8; ++i) {
        int g = g0 + r0 + i;
        if (g < nrows) {
            float4 o;
            o.x = fmaxf(acc[i].x + bv.x, 0.f);
            o.y = fmaxf(acc[i].y + bv.y, 0.f);
            o.z = fmaxf(acc[i].z + bv.z, 0.f);
            o.w = fmaxf(acc[i].w + bv.w, 0.f);
            *(float4*)&outp[(size_t)g * 64 + c0] = o;
        }
    }
}

// ---------------- pred-path factorization ----------------
// z@W1 = (h@W1[:64])[a] + (h@W1[64:])[b].
// k_uv: UV GEMM, M=100k K=64 N=128 (U cols 0..63, V cols 64..127), 8x8 thread
// tile. K=64 staged once, no K-loop. A stored k-major with XOR swizzle
// sw=(k>>2)*4. Left at 64 KB LDS as a same-structure control for the k_nn
// LDS-diet experiment.

__global__ __launch_bounds__(256, 2) void k_uv(
    const float* __restrict__ H, const float* __restrict__ W1,
    float* __restrict__ U, float* __restrict__ V, int nrows)
{
    __shared__ float AT[64 * 128];   // [k][row^sw], 32 KB
    __shared__ float Wm[64 * 128];   // [k][col],    32 KB
    const int t = threadIdx.x;
    const int g0 = blockIdx.x * 128;

    // stage Wc[k][j]: j<64 -> W1[k][j] (U half), else W1[64+k][j-64] (V half)
    #pragma unroll
    for (int p = 0; p < 8; ++p) {
        int li = p * 256 + t;          // 0..2047
        int k = li >> 5;               // 0..63
        int j4 = (li & 31) * 4;        // 0..124
        float4 wv = (j4 < 64) ? ld4(W1 + k * 64 + j4)
                              : ld4(W1 + (64 + k) * 64 + (j4 - 64));
        *(float4*)&Wm[k * 128 + j4] = wv;
    }
    // stage A transposed + swizzled: AT[k][r ^ ((k>>2)*4)] = H[g0+r][k]
    #pragma unroll
    for (int p = 0; p < 8; ++p) {
        int li = p * 256 + t;          // 128 rows x 16 col4-groups
        int r = li >> 4;               // 0..127
        int c4 = (li & 15) * 4;        // 0..60
        int g = g0 + r; if (g > nrows - 1) g = nrows - 1;
        float4 av = ld4(H + (size_t)g * 64 + c4);
        AT[(c4    ) * 128 + (r ^ (((c4    ) >> 2) * 4))] = av.x;
        AT[(c4 + 1) * 128 + (r ^ (((c4 + 1) >> 2) * 4))] = av.y;
        AT[(c4 + 2) * 128 + (r ^ (((c4 + 2) >> 2) * 4))] = av.z;
        AT[(c4 + 3) * 128 + (r ^ (((c4 + 3) >> 2) * 4))] = av.w;
    }
    __syncthreads();

    const int tc = t & 15, tr = t >> 4;
    const int c0 = tc * 4;             // U cols c0..c0+3, V cols 64+c0..+3
    const int r0 = tr * 8;             // rows r0..r0+7
    float4 accA[8], accB[8];
    #pragma unroll
    for (int i = 0; i < 8; ++i) {
        accA[i] = make_float4(0.f, 0.f, 0.f, 0.f);
        accB[i] = make_float4(0.f, 0.f, 0.f, 0.f);
    }

    #pragma unroll 4
    for (int k = 0; k < 64; ++k) {
        const float* arow = &AT[k * 128];
        int sw = (k >> 2) * 4;
        float4 a0 = ld4(arow + ((r0    ) ^ sw));   // rows r0..r0+3 at this k
        float4 a1 = ld4(arow + ((r0 + 4) ^ sw));   // rows r0+4..r0+7
        float4 w0 = ld4(&Wm[k * 128 + c0]);        // U cols
        float4 w1 = ld4(&Wm[k * 128 + 64 + c0]);   // V cols
        fma4(accA[0], a0.x, w0); fma4(accB[0], a0.x, w1);
        fma4(accA[1], a0.y, w0); fma4(accB[1], a0.y, w1);
        fma4(accA[2], a0.z, w0); fma4(accB[2], a0.z, w1);
        fma4(accA[3], a0.w, w0); fma4(accB[3], a0.w, w1);
        fma4(accA[4], a1.x, w0); fma4(accB[4], a1.x, w1);
        fma4(accA[5], a1.y, w0); fma4(accB[5], a1.y, w1);
        fma4(accA[6], a1.z, w0); fma4(accB[6], a1.z, w1);
        fma4(accA[7], a1.w, w0); fma4(accB[7], a1.w, w1);
    }

    #pragma unroll
    for (int i = 0; i < 8; ++i) {
        int g = g0 + r0 + i;
        if (g < nrows) {
            *(float4*)&U[(size_t)g * 64 + c0] = accA[i];
            *(float4*)&V[(size_t)g * 64 + c0] = accB[i];
        }
    }
}

// k_pred: out[p] = relu(U[a] + V[b] + b1) . W2 + b2 — pure gather-reduce.
// 16 lanes per pair, 256 B coalesced row per gather, shfl-reduce width 16.
__global__ __launch_bounds__(256) void k_pred(
    const float* __restrict__ U, const float* __restrict__ V,
    const int* __restrict__ pidx, const float* __restrict__ b1,
    const float* __restrict__ W2, const float* __restrict__ b2,
    float* __restrict__ outp, int np)
{
    const int t = threadIdx.x;
    const int lg = t & 15;
    const int p = blockIdx.x * 16 + (t >> 4);
    float4 bv = ld4(b1 + lg * 4);
    float4 wv = ld4(W2 + lg * 4);
    if (p >= np) return;
    int2 ab = ((const int2*)pidx)[p];
    float4 u = ld4(U + (size_t)ab.x * 64 + lg * 4);
    float4 v = ld4(V + (size_t)ab.y * 64 + lg * 4);
    float zx = fmaxf(u.x + v.x + bv.x, 0.f);
    float zy = fmaxf(u.y + v.y + bv.y, 0.f);
    float zz = fmaxf(u.z + v.z + bv.z, 0.f);
    float zw = fmaxf(u.w + v.w + bv.w, 0.f);
    float s = zx * wv.x + zy * wv.y + zz * wv.z + zw * wv.w;
    s += __shfl_down(s, 8, 16);
    s += __shfl_down(s, 4, 16);
    s += __shfl_down(s, 2, 16);
    s += __shfl_down(s, 1, 16);
    if (lg == 0) outp[p] = s + b2[0];
}

// ---------------- launch ----------------

extern "C" void kernel_launch(void* const* d_in, const int* in_sizes, int n_in,
                              void* d_out, int out_size, void* d_ws, size_t ws_size,
                              hipStream_t stream) {
    const float* x    = (const float*)d_in[0];
    const int*   edges= (const int*)d_in[1];
    const int*   pair = (const int*)d_in[2];
    const float* encW = (const float*)d_in[3];
    const float* encb = (const float*)d_in[4];
    const float* Wl   = (const float*)d_in[5];
    const float* bl   = (const float*)d_in[6];
    const float* Wr   = (const float*)d_in[7];
    const float* W1   = (const float*)d_in[8];
    const float* b1   = (const float*)d_in[9];
    const float* W2   = (const float*)d_in[10];
    const float* b2   = (const float*)d_in[11];
    float* out = (float*)d_out;

    const int N = N_NODES_C, E = N_EDGES_C, P = N_PAIRS_C;
    const int* dst = edges + E;
    const int M = NBKT * NB_S;

    char* w = (char*)d_ws;
    auto alloc = [&](size_t bytes) { char* p = w; w += (bytes + 255) & ~(size_t)255; return p; };
    int*   rowptr = (int*)alloc((size_t)(N + 1) * 4);
    int*   histT  = (int*)alloc((size_t)M * 4);
    int*   offs   = (int*)alloc((size_t)M * 4);
    int*   bsums  = (int*)alloc(128 * 4);
    float* invd   = (float*)alloc((size_t)N * 4);
    int*   adj    = (int*)alloc((size_t)E * 4);
    float* h0     = (float*)alloc((size_t)N * HID_C * 4);
    float* h1     = (float*)alloc((size_t)N * HID_C * 4);
    float* agg    = (float*)alloc((size_t)N * HID_C * 4);
    int2*  staging= (int2*)agg;

    int nscan = (M + SCAN_ELEMS - 1) / SCAN_ELEMS;

    hipLaunchKernelGGL(k_hist, dim3(NB_S), dim3(256), 0, stream, dst, histT, E);
    hipLaunchKernelGGL(k_scan_partial, dim3(nscan), dim3(SCAN_TPB), 0, stream, histT, offs, bsums, M);
    hipLaunchKernelGGL(k_scan_blocks, dim3(1), dim3(128), 0, stream, bsums, nscan);
    hipLaunchKernelGGL(k_scan_addg, dim3((M + 255) / 256), dim3(256), 0, stream, offs, bsums, M);
    hipLaunchKernelGGL(k_scatter, dim3(NB_S), dim3(256), 0, stream, edges, offs, staging, E);
    hipLaunchKernelGGL(k_bucket_fill, dim3(NBKT), dim3(256), 0, stream, staging, offs, rowptr, invd, adj, N, E);

    const int NB128 = (N + 127) / 128;

    k_nn<0><<<dim3(NB128), dim3(256), 0, stream>>>(
        x, nullptr, encW, nullptr, encb, h0, N);

    float* hc = h0; float* hn = h1;
    for (int l = 0; l < 3; l++) {
        hipLaunchKernelGGL(k_aggregate, dim3((N + 3) / 4), dim3(256), 0, stream,
                           rowptr, adj, invd, hc, agg, N);
        k_nn<1><<<dim3(NB128), dim3(256), 0, stream>>>(
            agg, hc, Wl + (size_t)l * 64 * 64, Wr + (size_t)l * 64 * 64,
            bl + (size_t)l * 64, hn, N);
        float* tswap = hc; hc = hn; hn = tswap;
    }

    // pred path: UV = h @ [W1_top | W1_bot], then per-pair gather-reduce.
    // U reuses agg (staging long dead), V reuses the retired h buffer (hn).
    float* Ubuf = agg;
    float* Vbuf = hn;
    const int NB_UV = (N + 127) / 128;
    hipLaunchKernelGGL(k_uv, dim3(NB_UV), dim3(256), 0, stream, hc, W1, Ubuf, Vbuf, N);
    hipLaunchKernelGGL(k_pred, dim3((P + 15) / 16), dim3(256), 0, stream,
                       Ubuf, Vbuf, pair, b1, W2, b2, out, P);
}

// Round 7
// 440.401 us; speedup vs baseline: 1.5754x; 1.0490x over previous
//
#include <hip/hip_runtime.h>
#include <hip/hip_fp16.h>
#include <cstdint>
#include <cstddef>

#define N_NODES_C 100000
#define N_EDGES_C 1250000
#define N_PAIRS_C 200000
#define IN_DIM_C 128
#define HID_C 64

// graph-build geometry
#define NB_S 256
#define BSH 9
#define NPB 512
#define NBKT 196
#define SEG_CAP 8192

// ---------------- scan helpers ----------------

#define SCAN_TPB 256
#define SCAN_IPT 4
#define SCAN_ELEMS 1024

__global__ void k_scan_partial(const int* __restrict__ in, int* __restrict__ outp,
                               int* __restrict__ blocksums, int n) {
    __shared__ int sd[SCAN_TPB];
    int tid = threadIdx.x;
    int base = blockIdx.x * SCAN_ELEMS + tid * SCAN_IPT;
    int v[SCAN_IPT]; int s = 0;
    for (int k = 0; k < SCAN_IPT; k++) { int idx = base + k; v[k] = (idx < n) ? in[idx] : 0; s += v[k]; }
    sd[tid] = s;
    __syncthreads();
    for (int off = 1; off < SCAN_TPB; off <<= 1) {
        int t = (tid >= off) ? sd[tid - off] : 0;
        __syncthreads();
        sd[tid] += t;
        __syncthreads();
    }
    int excl = sd[tid] - s;
    for (int k = 0; k < SCAN_IPT; k++) { int idx = base + k; if (idx < n) outp[idx] = excl; excl += v[k]; }
    if (tid == SCAN_TPB - 1) blocksums[blockIdx.x] = sd[tid];
}

__global__ void k_scan_blocks(int* __restrict__ bs, int nb) {
    __shared__ int sd[128];
    int t = threadIdx.x;
    int v = (t < nb) ? bs[t] : 0;
    sd[t] = v;
    __syncthreads();
    for (int off = 1; off < 128; off <<= 1) {
        int u = (t >= off) ? sd[t - off] : 0;
        __syncthreads();
        sd[t] += u;
        __syncthreads();
    }
    if (t < nb) bs[t] = sd[t] - v;
}

__global__ void k_scan_addg(int* __restrict__ arr, const int* __restrict__ bs, int n) {
    int i = blockIdx.x * blockDim.x + threadIdx.x;
    if (i < n) arr[i] += bs[i >> 10];
}

// ---------------- graph build: two-level counting sort ----------------

__global__ __launch_bounds__(256) void k_hist(const int* __restrict__ dst,
                                              int* __restrict__ histT, int e) {
    __shared__ int lh[NBKT];
    int tid = threadIdx.x, k = blockIdx.x;
    if (tid < NBKT) lh[tid] = 0;
    __syncthreads();
    int chunk = (e + NB_S - 1) / NB_S;
    int i0 = k * chunk, i1 = min(i0 + chunk, e);
    for (int i = i0 + tid; i < i1; i += 256) atomicAdd(&lh[dst[i] >> BSH], 1);
    __syncthreads();
    if (tid < NBKT) histT[tid * NB_S + k] = lh[tid];
}

__global__ __launch_bounds__(256) void k_scatter(const int* __restrict__ edges,
                                                 const int* __restrict__ offs,
                                                 int2* __restrict__ staging, int e) {
    __shared__ int cur[NBKT];
    int tid = threadIdx.x, k = blockIdx.x;
    if (tid < NBKT) cur[tid] = offs[tid * NB_S + k];
    __syncthreads();
    int chunk = (e + NB_S - 1) / NB_S;
    int i0 = k * chunk, i1 = min(i0 + chunk, e);
    for (int i = i0 + tid; i < i1; i += 256) {
        int s = edges[i];
        int d = edges[e + i];
        int p = atomicAdd(&cur[d >> BSH], 1);
        staging[p] = make_int2(s, d);
    }
}

__global__ __launch_bounds__(256) void k_bucket_fill(const int2* __restrict__ staging,
        const int* __restrict__ offs, int* __restrict__ rowptr,
        float* __restrict__ invd, int* __restrict__ adj, int n, int e) {
    __shared__ int ldeg[NPB];
    __shared__ int lrow[NPB];
    __shared__ int ps[256];
    __shared__ int lseg[SEG_CAP];
    int tid = threadIdx.x, b = blockIdx.x;
    int n0 = b << BSH;
    int nn = min(NPB, n - n0);
    int segBeg = offs[b * NB_S];
    int segEnd = (b == NBKT - 1) ? e : offs[(b + 1) * NB_S];

    ldeg[tid] = 0; ldeg[tid + 256] = 0;
    __syncthreads();
    for (int i = segBeg + tid; i < segEnd; i += 256)
        atomicAdd(&ldeg[staging[i].y - n0], 1);
    __syncthreads();

    int a0 = ldeg[2 * tid], a1 = ldeg[2 * tid + 1];
    int s = a0 + a1;
    ps[tid] = s;
    __syncthreads();
    for (int off = 1; off < 256; off <<= 1) {
        int t = (tid >= off) ? ps[tid - off] : 0;
        __syncthreads();
        ps[tid] += t;
        __syncthreads();
    }
    int excl = ps[tid] - s;
    lrow[2 * tid] = excl;
    lrow[2 * tid + 1] = excl + a0;
    __syncthreads();

    for (int j = tid; j < nn; j += 256) {
        rowptr[n0 + j] = segBeg + lrow[j];
        int d = ldeg[j];
        invd[n0 + j] = (d > 0) ? (1.0f / (float)d) : 0.0f;
    }
    if (b == NBKT - 1 && tid == 0) rowptr[n] = e;
    __syncthreads();

    for (int i = segBeg + tid; i < segEnd; i += 256) {
        int2 ed = staging[i];
        int p = atomicAdd(&lrow[ed.y - n0], 1);
        if (p < SEG_CAP) lseg[p] = ed.x;
        else adj[segBeg + p] = ed.x;
    }
    __syncthreads();

    int m = segEnd - segBeg; if (m > SEG_CAP) m = SEG_CAP;
    for (int p = tid; p < m; p += 256) adj[segBeg + p] = lseg[p];
}

// ---------------- aggregation ----------------
// R2/R3 PROVEN STRUCTURE (was 51.5 us on f32). This round's single change:
// gather from an fp16 SHADOW of h (row = 128 B = ONE cache line, was 256 B =
// two). R4 proved fusion kills it (concurrency-bound); R5 proved instruction
// shaving is free-but-useless (memory-system bound at 142 MB past-L2). Only
// fewer-bytes can move it: fp16 halves line count AND doubles effective L2
// capacity. Precision: fp16 only on the neighbor-mean input; self path and
// weights stay f32.

__global__ __launch_bounds__(256) void k_aggregate(const int* __restrict__ rowptr,
        const int* __restrict__ adj, const float* __restrict__ invd,
        const __half* __restrict__ hin16, float* __restrict__ agg, int n) {
    int wid = threadIdx.x >> 6, lane = threadIdx.x & 63;
    int node = blockIdx.x * 4 + wid;
    if (node >= n) return;
    int beg = rowptr[node], end = rowptr[node + 1];
    float acc = 0.0f;
    for (int e = beg; e < end; e += 8) {
        int idx[8];
        #pragma unroll
        for (int j = 0; j < 8; ++j) {
            int ee = e + j;
            idx[j] = adj[ee < end ? ee : end - 1];
        }
        float v[8];
        #pragma unroll
        for (int j = 0; j < 8; ++j)
            v[j] = __half2float(hin16[(size_t)idx[j] * HID_C + lane]);
        #pragma unroll
        for (int j = 0; j < 8; ++j) acc += (e + j < end) ? v[j] : 0.0f;
    }
    agg[(size_t)node * HID_C + lane] = acc * invd[node];
}

// ---------------- helpers ----------------

__device__ __forceinline__ float4 ld4(const float* p) { return *(const float4*)p; }

__device__ __forceinline__ void fma4(float4& acc, float sc, const float4& wv) {
    acc.x = fmaf(sc, wv.x, acc.x);
    acc.y = fmaf(sc, wv.y, acc.y);
    acc.z = fmaf(sc, wv.z, acc.z);
    acc.w = fmaf(sc, wv.w, acc.w);
}

// ---------------- k_nn: enc/layer GEMM (8-row x 4-col thread tile) -----------
// BM=128, BN=64, K=128 as two K=64 chunks. Wm staged per chunk (16 KB):
// AT 32 KB + Wm 16 KB = 48 KB -> 3 blocks/CU. XOR swizzle sw=(k>>2)*4.
// NEW: optional fp16 mirror write (out16) feeding the next layer's gather.
// MODE 0: out = relu(x @ encW + b)            (A1 = x, row stride 128)
// MODE 1: out = relu(agg @ Ws1 + h @ Ws2 + b) (A1 = agg, A2 = h, stride 64)

template<int MODE>
__global__ __launch_bounds__(256, 2) void k_nn(
    const float* __restrict__ A1, const float* __restrict__ A2,
    const float* __restrict__ Ws1, const float* __restrict__ Ws2,
    const float* __restrict__ bias,
    float* __restrict__ outp, __half* __restrict__ out16, int nrows)
{
    __shared__ float AT[64 * 128];   // per-chunk [k][r^sw], 32 KB
    __shared__ float Wm[64 * 64];    // per-chunk [k][c],    16 KB
    const int t = threadIdx.x;
    const int g0 = blockIdx.x * 128;

    const int tc = t & 15, tr = t >> 4;
    const int c0 = tc * 4;             // out cols c0..c0+3
    const int r0 = tr * 8;             // out rows r0..r0+7
    float4 acc[8];
    #pragma unroll
    for (int i = 0; i < 8; ++i) acc[i] = make_float4(0.f, 0.f, 0.f, 0.f);

    #pragma unroll
    for (int chunk = 0; chunk < 2; ++chunk) {
        // stage Wm for this chunk: 64x64 = 1024 float4
        #pragma unroll
        for (int p = 0; p < 4; ++p) {
            int li = p * 256 + t;          // 0..1023
            int k = li >> 4;               // 0..63
            int c4 = (li & 15) * 4;        // 0..60
            const float* wsrc;
            if (MODE == 0) wsrc = Ws1 + (chunk * 64 + k) * 64 + c4;
            else           wsrc = (chunk == 0) ? (Ws1 + k * 64 + c4)
                                               : (Ws2 + k * 64 + c4);
            *(float4*)&Wm[k * 64 + c4] = ld4(wsrc);
        }
        // stage AT[k][r ^ ((k>>2)*4)] for this K-chunk
        #pragma unroll
        for (int p = 0; p < 8; ++p) {
            int li = p * 256 + t;          // 128 rows x 16 k4-groups
            int r = li >> 4;               // 0..127
            int c4 = (li & 15) * 4;        // 0..60 (k within chunk)
            int g = g0 + r; if (g > nrows - 1) g = nrows - 1;
            float4 av;
            if (MODE == 0) av = ld4(A1 + (size_t)g * 128 + chunk * 64 + c4);
            else           av = (chunk == 0) ? ld4(A1 + (size_t)g * 64 + c4)
                                             : ld4(A2 + (size_t)g * 64 + c4);
            AT[(c4    ) * 128 + (r ^ (((c4    ) >> 2) * 4))] = av.x;
            AT[(c4 + 1) * 128 + (r ^ (((c4 + 1) >> 2) * 4))] = av.y;
            AT[(c4 + 2) * 128 + (r ^ (((c4 + 2) >> 2) * 4))] = av.z;
            AT[(c4 + 3) * 128 + (r ^ (((c4 + 3) >> 2) * 4))] = av.w;
        }
        __syncthreads();

        #pragma unroll 4
        for (int k = 0; k < 64; ++k) {
            const float* arow = &AT[k * 128];
            int sw = (k >> 2) * 4;
            float4 a0 = ld4(arow + ((r0    ) ^ sw));   // rows r0..r0+3
            float4 a1 = ld4(arow + ((r0 + 4) ^ sw));   // rows r0+4..r0+7
            float4 wv = ld4(&Wm[k * 64 + c0]);
            fma4(acc[0], a0.x, wv); fma4(acc[1], a0.y, wv);
            fma4(acc[2], a0.z, wv); fma4(acc[3], a0.w, wv);
            fma4(acc[4], a1.x, wv); fma4(acc[5], a1.y, wv);
            fma4(acc[6], a1.z, wv); fma4(acc[7], a1.w, wv);
        }
        __syncthreads();   // protect AT/Wm before restage
    }

    float4 bv = ld4(bias + c0);
    #pragma unroll
    for (int i = 0; i < 8; ++i) {
        int g = g0 + r0 + i;
        if (g < nrows) {
            float4 o;
            o.x = fmaxf(acc[i].x + bv.x, 0.f);
            o.y = fmaxf(acc[i].y + bv.y, 0.f);
            o.z = fmaxf(acc[i].z + bv.z, 0.f);
            o.w = fmaxf(acc[i].w + bv.w, 0.f);
            *(float4*)&outp[(size_t)g * 64 + c0] = o;
            if (out16) {
                __half2 p0 = __floats2half2_rn(o.x, o.y);
                __half2 p1 = __floats2half2_rn(o.z, o.w);
                *(__half2*)&out16[(size_t)g * 64 + c0]     = p0;
                *(__half2*)&out16[(size_t)g * 64 + c0 + 2] = p1;
            }
        }
    }
}

// ---------------- pred-path factorization ----------------
// z@W1 = (h@W1[:64])[a] + (h@W1[64:])[b].
// k_uv: UV GEMM, M=100k K=64 N=128 (U cols 0..63, V cols 64..127), 8x8 thread
// tile. K=64 staged once, no K-loop. A stored k-major with XOR swizzle
// sw=(k>>2)*4. All f32 (pred path precision preserved).

__global__ __launch_bounds__(256, 2) void k_uv(
    const float* __restrict__ H, const float* __restrict__ W1,
    float* __restrict__ U, float* __restrict__ V, int nrows)
{
    __shared__ float AT[64 * 128];   // [k][row^sw], 32 KB
    __shared__ float Wm[64 * 128];   // [k][col],    32 KB
    const int t = threadIdx.x;
    const int g0 = blockIdx.x * 128;

    // stage Wc[k][j]: j<64 -> W1[k][j] (U half), else W1[64+k][j-64] (V half)
    #pragma unroll
    for (int p = 0; p < 8; ++p) {
        int li = p * 256 + t;          // 0..2047
        int k = li >> 5;               // 0..63
        int j4 = (li & 31) * 4;        // 0..124
        float4 wv = (j4 < 64) ? ld4(W1 + k * 64 + j4)
                              : ld4(W1 + (64 + k) * 64 + (j4 - 64));
        *(float4*)&Wm[k * 128 + j4] = wv;
    }
    // stage A transposed + swizzled: AT[k][r ^ ((k>>2)*4)] = H[g0+r][k]
    #pragma unroll
    for (int p = 0; p < 8; ++p) {
        int li = p * 256 + t;          // 128 rows x 16 col4-groups
        int r = li >> 4;               // 0..127
        int c4 = (li & 15) * 4;        // 0..60
        int g = g0 + r; if (g > nrows - 1) g = nrows - 1;
        float4 av = ld4(H + (size_t)g * 64 + c4);
        AT[(c4    ) * 128 + (r ^ (((c4    ) >> 2) * 4))] = av.x;
        AT[(c4 + 1) * 128 + (r ^ (((c4 + 1) >> 2) * 4))] = av.y;
        AT[(c4 + 2) * 128 + (r ^ (((c4 + 2) >> 2) * 4))] = av.z;
        AT[(c4 + 3) * 128 + (r ^ (((c4 + 3) >> 2) * 4))] = av.w;
    }
    __syncthreads();

    const int tc = t & 15, tr = t >> 4;
    const int c0 = tc * 4;             // U cols c0..c0+3, V cols 64+c0..+3
    const int r0 = tr * 8;             // rows r0..r0+7
    float4 accA[8], accB[8];
    #pragma unroll
    for (int i = 0; i < 8; ++i) {
        accA[i] = make_float4(0.f, 0.f, 0.f, 0.f);
        accB[i] = make_float4(0.f, 0.f, 0.f, 0.f);
    }

    #pragma unroll 4
    for (int k = 0; k < 64; ++k) {
        const float* arow = &AT[k * 128];
        int sw = (k >> 2) * 4;
        float4 a0 = ld4(arow + ((r0    ) ^ sw));   // rows r0..r0+3 at this k
        float4 a1 = ld4(arow + ((r0 + 4) ^ sw));   // rows r0+4..r0+7
        float4 w0 = ld4(&Wm[k * 128 + c0]);        // U cols
        float4 w1 = ld4(&Wm[k * 128 + 64 + c0]);   // V cols
        fma4(accA[0], a0.x, w0); fma4(accB[0], a0.x, w1);
        fma4(accA[1], a0.y, w0); fma4(accB[1], a0.y, w1);
        fma4(accA[2], a0.z, w0); fma4(accB[2], a0.z, w1);
        fma4(accA[3], a0.w, w0); fma4(accB[3], a0.w, w1);
        fma4(accA[4], a1.x, w0); fma4(accB[4], a1.x, w1);
        fma4(accA[5], a1.y, w0); fma4(accB[5], a1.y, w1);
        fma4(accA[6], a1.z, w0); fma4(accB[6], a1.z, w1);
        fma4(accA[7], a1.w, w0); fma4(accB[7], a1.w, w1);
    }

    #pragma unroll
    for (int i = 0; i < 8; ++i) {
        int g = g0 + r0 + i;
        if (g < nrows) {
            *(float4*)&U[(size_t)g * 64 + c0] = accA[i];
            *(float4*)&V[(size_t)g * 64 + c0] = accB[i];
        }
    }
}

// k_pred: out[p] = relu(U[a] + V[b] + b1) . W2 + b2 — pure gather-reduce.
// 16 lanes per pair, 256 B coalesced row per gather, shfl-reduce width 16.
__global__ __launch_bounds__(256) void k_pred(
    const float* __restrict__ U, const float* __restrict__ V,
    const int* __restrict__ pidx, const float* __restrict__ b1,
    const float* __restrict__ W2, const float* __restrict__ b2,
    float* __restrict__ outp, int np)
{
    const int t = threadIdx.x;
    const int lg = t & 15;
    const int p = blockIdx.x * 16 + (t >> 4);
    float4 bv = ld4(b1 + lg * 4);
    float4 wv = ld4(W2 + lg * 4);
    if (p >= np) return;
    int2 ab = ((const int2*)pidx)[p];
    float4 u = ld4(U + (size_t)ab.x * 64 + lg * 4);
    float4 v = ld4(V + (size_t)ab.y * 64 + lg * 4);
    float zx = fmaxf(u.x + v.x + bv.x, 0.f);
    float zy = fmaxf(u.y + v.y + bv.y, 0.f);
    float zz = fmaxf(u.z + v.z + bv.z, 0.f);
    float zw = fmaxf(u.w + v.w + bv.w, 0.f);
    float s = zx * wv.x + zy * wv.y + zz * wv.z + zw * wv.w;
    s += __shfl_down(s, 8, 16);
    s += __shfl_down(s, 4, 16);
    s += __shfl_down(s, 2, 16);
    s += __shfl_down(s, 1, 16);
    if (lg == 0) outp[p] = s + b2[0];
}

// ---------------- launch ----------------

extern "C" void kernel_launch(void* const* d_in, const int* in_sizes, int n_in,
                              void* d_out, int out_size, void* d_ws, size_t ws_size,
                              hipStream_t stream) {
    const float* x    = (const float*)d_in[0];
    const int*   edges= (const int*)d_in[1];
    const int*   pair = (const int*)d_in[2];
    const float* encW = (const float*)d_in[3];
    const float* encb = (const float*)d_in[4];
    const float* Wl   = (const float*)d_in[5];
    const float* bl   = (const float*)d_in[6];
    const float* Wr   = (const float*)d_in[7];
    const float* W1   = (const float*)d_in[8];
    const float* b1   = (const float*)d_in[9];
    const float* W2   = (const float*)d_in[10];
    const float* b2   = (const float*)d_in[11];
    float* out = (float*)d_out;

    const int N = N_NODES_C, E = N_EDGES_C, P = N_PAIRS_C;
    const int* dst = edges + E;
    const int M = NBKT * NB_S;

    char* w = (char*)d_ws;
    auto alloc = [&](size_t bytes) { char* p = w; w += (bytes + 255) & ~(size_t)255; return p; };
    int*   rowptr = (int*)alloc((size_t)(N + 1) * 4);
    int*   histT  = (int*)alloc((size_t)M * 4);
    int*   offs   = (int*)alloc((size_t)M * 4);
    int*   bsums  = (int*)alloc(128 * 4);
    float* invd   = (float*)alloc((size_t)N * 4);
    int*   adj    = (int*)alloc((size_t)E * 4);
    float* h0     = (float*)alloc((size_t)N * HID_C * 4);
    float* h1     = (float*)alloc((size_t)N * HID_C * 4);
    float* agg    = (float*)alloc((size_t)N * HID_C * 4);
    __half* h16a  = (__half*)alloc((size_t)N * HID_C * 2);
    __half* h16b  = (__half*)alloc((size_t)N * HID_C * 2);
    int2*  staging= (int2*)agg;

    int nscan = (M + SCAN_ELEMS - 1) / SCAN_ELEMS;

    hipLaunchKernelGGL(k_hist, dim3(NB_S), dim3(256), 0, stream, dst, histT, E);
    hipLaunchKernelGGL(k_scan_partial, dim3(nscan), dim3(SCAN_TPB), 0, stream, histT, offs, bsums, M);
    hipLaunchKernelGGL(k_scan_blocks, dim3(1), dim3(128), 0, stream, bsums, nscan);
    hipLaunchKernelGGL(k_scan_addg, dim3((M + 255) / 256), dim3(256), 0, stream, offs, bsums, M);
    hipLaunchKernelGGL(k_scatter, dim3(NB_S), dim3(256), 0, stream, edges, offs, staging, E);
    hipLaunchKernelGGL(k_bucket_fill, dim3(NBKT), dim3(256), 0, stream, staging, offs, rowptr, invd, adj, N, E);

    const int NB128 = (N + 127) / 128;

    k_nn<0><<<dim3(NB128), dim3(256), 0, stream>>>(
        x, nullptr, encW, nullptr, encb, h0, h16a, N);

    float* hc = h0; float* hn = h1;
    __half* h16c = h16a; __half* h16n = h16b;
    for (int l = 0; l < 3; l++) {
        hipLaunchKernelGGL(k_aggregate, dim3((N + 3) / 4), dim3(256), 0, stream,
                           rowptr, adj, invd, h16c, agg, N);
        // layer 2 (l==2) output never feeds another aggregate: skip fp16 mirror
        k_nn<1><<<dim3(NB128), dim3(256), 0, stream>>>(
            agg, hc, Wl + (size_t)l * 64 * 64, Wr + (size_t)l * 64 * 64,
            bl + (size_t)l * 64, hn, (l < 2) ? h16n : (__half*)nullptr, N);
        float* tswap = hc; hc = hn; hn = tswap;
        __half* t16 = h16c; h16c = h16n; h16n = t16;
    }

    // pred path: UV = h @ [W1_top | W1_bot], then per-pair gather-reduce.
    // U reuses agg (staging long dead), V reuses the retired h buffer (hn).
    float* Ubuf = agg;
    float* Vbuf = hn;
    const int NB_UV = (N + 127) / 128;
    hipLaunchKernelGGL(k_uv, dim3(NB_UV), dim3(256), 0, stream, hc, W1, Ubuf, Vbuf, N);
    hipLaunchKernelGGL(k_pred, dim3((P + 15) / 16), dim3(256), 0, stream,
                       Ubuf, Vbuf, pair, b1, W2, b2, out, P);
}

// Round 8
// 409.517 us; speedup vs baseline: 1.6942x; 1.0754x over previous
//
#include <hip/hip_runtime.h>
#include <hip/hip_fp16.h>
#include <cstdint>
#include <cstddef>

#define N_NODES_C 100000
#define N_EDGES_C 1250000
#define N_PAIRS_C 200000
#define IN_DIM_C 128
#define HID_C 64

// graph-build geometry
#define NB_S 256
#define BSH 9
#define NPB 512
#define NBKT 196
#define SEG_CAP 8192

// ---------------- scan helpers ----------------

#define SCAN_TPB 256
#define SCAN_IPT 4
#define SCAN_ELEMS 1024

__global__ void k_scan_partial(const int* __restrict__ in, int* __restrict__ outp,
                               int* __restrict__ blocksums, int n) {
    __shared__ int sd[SCAN_TPB];
    int tid = threadIdx.x;
    int base = blockIdx.x * SCAN_ELEMS + tid * SCAN_IPT;
    int v[SCAN_IPT]; int s = 0;
    for (int k = 0; k < SCAN_IPT; k++) { int idx = base + k; v[k] = (idx < n) ? in[idx] : 0; s += v[k]; }
    sd[tid] = s;
    __syncthreads();
    for (int off = 1; off < SCAN_TPB; off <<= 1) {
        int t = (tid >= off) ? sd[tid - off] : 0;
        __syncthreads();
        sd[tid] += t;
        __syncthreads();
    }
    int excl = sd[tid] - s;
    for (int k = 0; k < SCAN_IPT; k++) { int idx = base + k; if (idx < n) outp[idx] = excl; excl += v[k]; }
    if (tid == SCAN_TPB - 1) blocksums[blockIdx.x] = sd[tid];
}

__global__ void k_scan_blocks(int* __restrict__ bs, int nb) {
    __shared__ int sd[128];
    int t = threadIdx.x;
    int v = (t < nb) ? bs[t] : 0;
    sd[t] = v;
    __syncthreads();
    for (int off = 1; off < 128; off <<= 1) {
        int u = (t >= off) ? sd[t - off] : 0;
        __syncthreads();
        sd[t] += u;
        __syncthreads();
    }
    if (t < nb) bs[t] = sd[t] - v;
}

__global__ void k_scan_addg(int* __restrict__ arr, const int* __restrict__ bs, int n) {
    int i = blockIdx.x * blockDim.x + threadIdx.x;
    if (i < n) arr[i] += bs[i >> 10];
}

// ---------------- graph build: two-level counting sort ----------------

__global__ __launch_bounds__(256) void k_hist(const int* __restrict__ dst,
                                              int* __restrict__ histT, int e) {
    __shared__ int lh[NBKT];
    int tid = threadIdx.x, k = blockIdx.x;
    if (tid < NBKT) lh[tid] = 0;
    __syncthreads();
    int chunk = (e + NB_S - 1) / NB_S;
    int i0 = k * chunk, i1 = min(i0 + chunk, e);
    for (int i = i0 + tid; i < i1; i += 256) atomicAdd(&lh[dst[i] >> BSH], 1);
    __syncthreads();
    if (tid < NBKT) histT[tid * NB_S + k] = lh[tid];
}

__global__ __launch_bounds__(256) void k_scatter(const int* __restrict__ edges,
                                                 const int* __restrict__ offs,
                                                 int2* __restrict__ staging, int e) {
    __shared__ int cur[NBKT];
    int tid = threadIdx.x, k = blockIdx.x;
    if (tid < NBKT) cur[tid] = offs[tid * NB_S + k];
    __syncthreads();
    int chunk = (e + NB_S - 1) / NB_S;
    int i0 = k * chunk, i1 = min(i0 + chunk, e);
    for (int i = i0 + tid; i < i1; i += 256) {
        int s = edges[i];
        int d = edges[e + i];
        int p = atomicAdd(&cur[d >> BSH], 1);
        staging[p] = make_int2(s, d);
    }
}

__global__ __launch_bounds__(256) void k_bucket_fill(const int2* __restrict__ staging,
        const int* __restrict__ offs, int* __restrict__ rowptr,
        float* __restrict__ invd, int* __restrict__ adj, int n, int e) {
    __shared__ int ldeg[NPB];
    __shared__ int lrow[NPB];
    __shared__ int ps[256];
    __shared__ int lseg[SEG_CAP];
    int tid = threadIdx.x, b = blockIdx.x;
    int n0 = b << BSH;
    int nn = min(NPB, n - n0);
    int segBeg = offs[b * NB_S];
    int segEnd = (b == NBKT - 1) ? e : offs[(b + 1) * NB_S];

    ldeg[tid] = 0; ldeg[tid + 256] = 0;
    __syncthreads();
    for (int i = segBeg + tid; i < segEnd; i += 256)
        atomicAdd(&ldeg[staging[i].y - n0], 1);
    __syncthreads();

    int a0 = ldeg[2 * tid], a1 = ldeg[2 * tid + 1];
    int s = a0 + a1;
    ps[tid] = s;
    __syncthreads();
    for (int off = 1; off < 256; off <<= 1) {
        int t = (tid >= off) ? ps[tid - off] : 0;
        __syncthreads();
        ps[tid] += t;
        __syncthreads();
    }
    int excl = ps[tid] - s;
    lrow[2 * tid] = excl;
    lrow[2 * tid + 1] = excl + a0;
    __syncthreads();

    for (int j = tid; j < nn; j += 256) {
        rowptr[n0 + j] = segBeg + lrow[j];
        int d = ldeg[j];
        invd[n0 + j] = (d > 0) ? (1.0f / (float)d) : 0.0f;
    }
    if (b == NBKT - 1 && tid == 0) rowptr[n] = e;
    __syncthreads();

    for (int i = segBeg + tid; i < segEnd; i += 256) {
        int2 ed = staging[i];
        int p = atomicAdd(&lrow[ed.y - n0], 1);
        if (p < SEG_CAP) lseg[p] = ed.x;
        else adj[segBeg + p] = ed.x;
    }
    __syncthreads();

    int m = segEnd - segBeg; if (m > SEG_CAP) m = SEG_CAP;
    for (int p = tid; p < m; p += 256) adj[segBeg + p] = lseg[p];
}

// ---------------- aggregation ----------------
// fp16-gather (R7 win: FETCH 142->67 MB). R7 counters: VALUBusy 65%, HBM 26%
// -> issue/VALU-bound. This round: TWO NODES PER WAVE. Lanes 0-31 = node A,
// lanes 32-63 = node B; each lane owns 2 columns via __half2 (32 lanes x 4 B
// = one full 128 B row per half-wave). One gather-load instruction serves two
// edges -> load-issues, clamps, addr VALU per edge HALVED; cvt/add unchanged;
// no cross-lane reduce (lane owns its columns; final write = coalesced
// float2). Cost: loop to max(degA,degB) ~ +16% masked iters (Poisson 12.5).
// History: R4 fusion 3.2x worse (concurrency-bound); R5 f32 quarter-split
// neutral-negative (memory-bound then); R7 fp16 -8%.

__global__ __launch_bounds__(256) void k_aggregate(const int* __restrict__ rowptr,
        const int* __restrict__ adj, const float* __restrict__ invd,
        const __half* __restrict__ hin16, float* __restrict__ agg, int n) {
    int wid = threadIdx.x >> 6, lane = threadIdx.x & 63;
    int nodeA = (blockIdx.x * 4 + wid) * 2;
    if (nodeA >= n) return;
    const int half = lane >> 5;        // 0: node A, 1: node B
    const int c2 = (lane & 31) * 2;    // columns c2, c2+1
    int node = nodeA + half;
    bool valid = node < n;
    int nodec = valid ? node : n - 1;
    int beg = rowptr[nodec], end = rowptr[nodec + 1];
    float accx = 0.f, accy = 0.f;
    for (int e = beg; e < end; e += 8) {
        int idx[8];
        #pragma unroll
        for (int j = 0; j < 8; ++j) {
            int ee = e + j;
            idx[j] = adj[ee < end ? ee : end - 1];
        }
        __half2 v[8];
        #pragma unroll
        for (int j = 0; j < 8; ++j)
            v[j] = *(const __half2*)&hin16[(size_t)idx[j] * HID_C + c2];
        #pragma unroll
        for (int j = 0; j < 8; ++j) {
            float2 f = __half22float2(v[j]);
            bool in = (e + j < end);
            accx += in ? f.x : 0.f;
            accy += in ? f.y : 0.f;
        }
    }
    if (valid) {
        float s = invd[node];
        *(float2*)&agg[(size_t)node * HID_C + c2] = make_float2(accx * s, accy * s);
    }
}

// ---------------- helpers ----------------

__device__ __forceinline__ float4 ld4(const float* p) { return *(const float4*)p; }

__device__ __forceinline__ void fma4(float4& acc, float sc, const float4& wv) {
    acc.x = fmaf(sc, wv.x, acc.x);
    acc.y = fmaf(sc, wv.y, acc.y);
    acc.z = fmaf(sc, wv.z, acc.z);
    acc.w = fmaf(sc, wv.w, acc.w);
}

// ---------------- k_nn: enc/layer GEMM (8-row x 4-col thread tile) -----------
// BM=128, BN=64, K=128 as two K=64 chunks. Wm staged per chunk (16 KB):
// AT 32 KB + Wm 16 KB = 48 KB -> 3 blocks/CU. XOR swizzle sw=(k>>2)*4.
// Optional fp16 mirror write (out16) feeding the next layer's gather.
// MODE 0: out = relu(x @ encW + b)            (A1 = x, row stride 128)
// MODE 1: out = relu(agg @ Ws1 + h @ Ws2 + b) (A1 = agg, A2 = h, stride 64)

template<int MODE>
__global__ __launch_bounds__(256, 2) void k_nn(
    const float* __restrict__ A1, const float* __restrict__ A2,
    const float* __restrict__ Ws1, const float* __restrict__ Ws2,
    const float* __restrict__ bias,
    float* __restrict__ outp, __half* __restrict__ out16, int nrows)
{
    __shared__ float AT[64 * 128];   // per-chunk [k][r^sw], 32 KB
    __shared__ float Wm[64 * 64];    // per-chunk [k][c],    16 KB
    const int t = threadIdx.x;
    const int g0 = blockIdx.x * 128;

    const int tc = t & 15, tr = t >> 4;
    const int c0 = tc * 4;             // out cols c0..c0+3
    const int r0 = tr * 8;             // out rows r0..r0+7
    float4 acc[8];
    #pragma unroll
    for (int i = 0; i < 8; ++i) acc[i] = make_float4(0.f, 0.f, 0.f, 0.f);

    #pragma unroll
    for (int chunk = 0; chunk < 2; ++chunk) {
        // stage Wm for this chunk: 64x64 = 1024 float4
        #pragma unroll
        for (int p = 0; p < 4; ++p) {
            int li = p * 256 + t;          // 0..1023
            int k = li >> 4;               // 0..63
            int c4 = (li & 15) * 4;        // 0..60
            const float* wsrc;
            if (MODE == 0) wsrc = Ws1 + (chunk * 64 + k) * 64 + c4;
            else           wsrc = (chunk == 0) ? (Ws1 + k * 64 + c4)
                                               : (Ws2 + k * 64 + c4);
            *(float4*)&Wm[k * 64 + c4] = ld4(wsrc);
        }
        // stage AT[k][r ^ ((k>>2)*4)] for this K-chunk
        #pragma unroll
        for (int p = 0; p < 8; ++p) {
            int li = p * 256 + t;          // 128 rows x 16 k4-groups
            int r = li >> 4;               // 0..127
            int c4 = (li & 15) * 4;        // 0..60 (k within chunk)
            int g = g0 + r; if (g > nrows - 1) g = nrows - 1;
            float4 av;
            if (MODE == 0) av = ld4(A1 + (size_t)g * 128 + chunk * 64 + c4);
            else           av = (chunk == 0) ? ld4(A1 + (size_t)g * 64 + c4)
                                             : ld4(A2 + (size_t)g * 64 + c4);
            AT[(c4    ) * 128 + (r ^ (((c4    ) >> 2) * 4))] = av.x;
            AT[(c4 + 1) * 128 + (r ^ (((c4 + 1) >> 2) * 4))] = av.y;
            AT[(c4 + 2) * 128 + (r ^ (((c4 + 2) >> 2) * 4))] = av.z;
            AT[(c4 + 3) * 128 + (r ^ (((c4 + 3) >> 2) * 4))] = av.w;
        }
        __syncthreads();

        #pragma unroll 4
        for (int k = 0; k < 64; ++k) {
            const float* arow = &AT[k * 128];
            int sw = (k >> 2) * 4;
            float4 a0 = ld4(arow + ((r0    ) ^ sw));   // rows r0..r0+3
            float4 a1 = ld4(arow + ((r0 + 4) ^ sw));   // rows r0+4..r0+7
            float4 wv = ld4(&Wm[k * 64 + c0]);
            fma4(acc[0], a0.x, wv); fma4(acc[1], a0.y, wv);
            fma4(acc[2], a0.z, wv); fma4(acc[3], a0.w, wv);
            fma4(acc[4], a1.x, wv); fma4(acc[5], a1.y, wv);
            fma4(acc[6], a1.z, wv); fma4(acc[7], a1.w, wv);
        }
        __syncthreads();   // protect AT/Wm before restage
    }

    float4 bv = ld4(bias + c0);
    #pragma unroll
    for (int i = 0; i < 8; ++i) {
        int g = g0 + r0 + i;
        if (g < nrows) {
            float4 o;
            o.x = fmaxf(acc[i].x + bv.x, 0.f);
            o.y = fmaxf(acc[i].y + bv.y, 0.f);
            o.z = fmaxf(acc[i].z + bv.z, 0.f);
            o.w = fmaxf(acc[i].w + bv.w, 0.f);
            *(float4*)&outp[(size_t)g * 64 + c0] = o;
            if (out16) {
                __half2 p0 = __floats2half2_rn(o.x, o.y);
                __half2 p1 = __floats2half2_rn(o.z, o.w);
                *(__half2*)&out16[(size_t)g * 64 + c0]     = p0;
                *(__half2*)&out16[(size_t)g * 64 + c0 + 2] = p1;
            }
        }
    }
}

// ---------------- pred-path factorization ----------------
// z@W1 = (h@W1[:64])[a] + (h@W1[64:])[b].
// k_uv: UV GEMM, M=100k K=64 N=128 (U cols 0..63, V cols 64..127), 8x8 thread
// tile. K=64 staged once, no K-loop. A stored k-major with XOR swizzle
// sw=(k>>2)*4. All f32 (pred path precision preserved).

__global__ __launch_bounds__(256, 2) void k_uv(
    const float* __restrict__ H, const float* __restrict__ W1,
    float* __restrict__ U, float* __restrict__ V, int nrows)
{
    __shared__ float AT[64 * 128];   // [k][row^sw], 32 KB
    __shared__ float Wm[64 * 128];   // [k][col],    32 KB
    const int t = threadIdx.x;
    const int g0 = blockIdx.x * 128;

    // stage Wc[k][j]: j<64 -> W1[k][j] (U half), else W1[64+k][j-64] (V half)
    #pragma unroll
    for (int p = 0; p < 8; ++p) {
        int li = p * 256 + t;          // 0..2047
        int k = li >> 5;               // 0..63
        int j4 = (li & 31) * 4;        // 0..124
        float4 wv = (j4 < 64) ? ld4(W1 + k * 64 + j4)
                              : ld4(W1 + (64 + k) * 64 + (j4 - 64));
        *(float4*)&Wm[k * 128 + j4] = wv;
    }
    // stage A transposed + swizzled: AT[k][r ^ ((k>>2)*4)] = H[g0+r][k]
    #pragma unroll
    for (int p = 0; p < 8; ++p) {
        int li = p * 256 + t;          // 128 rows x 16 col4-groups
        int r = li >> 4;               // 0..127
        int c4 = (li & 15) * 4;        // 0..60
        int g = g0 + r; if (g > nrows - 1) g = nrows - 1;
        float4 av = ld4(H + (size_t)g * 64 + c4);
        AT[(c4    ) * 128 + (r ^ (((c4    ) >> 2) * 4))] = av.x;
        AT[(c4 + 1) * 128 + (r ^ (((c4 + 1) >> 2) * 4))] = av.y;
        AT[(c4 + 2) * 128 + (r ^ (((c4 + 2) >> 2) * 4))] = av.z;
        AT[(c4 + 3) * 128 + (r ^ (((c4 + 3) >> 2) * 4))] = av.w;
    }
    __syncthreads();

    const int tc = t & 15, tr = t >> 4;
    const int c0 = tc * 4;             // U cols c0..c0+3, V cols 64+c0..+3
    const int r0 = tr * 8;             // rows r0..r0+7
    float4 accA[8], accB[8];
    #pragma unroll
    for (int i = 0; i < 8; ++i) {
        accA[i] = make_float4(0.f, 0.f, 0.f, 0.f);
        accB[i] = make_float4(0.f, 0.f, 0.f, 0.f);
    }

    #pragma unroll 4
    for (int k = 0; k < 64; ++k) {
        const float* arow = &AT[k * 128];
        int sw = (k >> 2) * 4;
        float4 a0 = ld4(arow + ((r0    ) ^ sw));   // rows r0..r0+3 at this k
        float4 a1 = ld4(arow + ((r0 + 4) ^ sw));   // rows r0+4..r0+7
        float4 w0 = ld4(&Wm[k * 128 + c0]);        // U cols
        float4 w1 = ld4(&Wm[k * 128 + 64 + c0]);   // V cols
        fma4(accA[0], a0.x, w0); fma4(accB[0], a0.x, w1);
        fma4(accA[1], a0.y, w0); fma4(accB[1], a0.y, w1);
        fma4(accA[2], a0.z, w0); fma4(accB[2], a0.z, w1);
        fma4(accA[3], a0.w, w0); fma4(accB[3], a0.w, w1);
        fma4(accA[4], a1.x, w0); fma4(accB[4], a1.x, w1);
        fma4(accA[5], a1.y, w0); fma4(accB[5], a1.y, w1);
        fma4(accA[6], a1.z, w0); fma4(accB[6], a1.z, w1);
        fma4(accA[7], a1.w, w0); fma4(accB[7], a1.w, w1);
    }

    #pragma unroll
    for (int i = 0; i < 8; ++i) {
        int g = g0 + r0 + i;
        if (g < nrows) {
            *(float4*)&U[(size_t)g * 64 + c0] = accA[i];
            *(float4*)&V[(size_t)g * 64 + c0] = accB[i];
        }
    }
}

// k_pred: out[p] = relu(U[a] + V[b] + b1) . W2 + b2 — pure gather-reduce.
// 16 lanes per pair, 256 B coalesced row per gather, shfl-reduce width 16.
__global__ __launch_bounds__(256) void k_pred(
    const float* __restrict__ U, const float* __restrict__ V,
    const int* __restrict__ pidx, const float* __restrict__ b1,
    const float* __restrict__ W2, const float* __restrict__ b2,
    float* __restrict__ outp, int np)
{
    const int t = threadIdx.x;
    const int lg = t & 15;
    const int p = blockIdx.x * 16 + (t >> 4);
    float4 bv = ld4(b1 + lg * 4);
    float4 wv = ld4(W2 + lg * 4);
    if (p >= np) return;
    int2 ab = ((const int2*)pidx)[p];
    float4 u = ld4(U + (size_t)ab.x * 64 + lg * 4);
    float4 v = ld4(V + (size_t)ab.y * 64 + lg * 4);
    float zx = fmaxf(u.x + v.x + bv.x, 0.f);
    float zy = fmaxf(u.y + v.y + bv.y, 0.f);
    float zz = fmaxf(u.z + v.z + bv.z, 0.f);
    float zw = fmaxf(u.w + v.w + bv.w, 0.f);
    float s = zx * wv.x + zy * wv.y + zz * wv.z + zw * wv.w;
    s += __shfl_down(s, 8, 16);
    s += __shfl_down(s, 4, 16);
    s += __shfl_down(s, 2, 16);
    s += __shfl_down(s, 1, 16);
    if (lg == 0) outp[p] = s + b2[0];
}

// ---------------- launch ----------------

extern "C" void kernel_launch(void* const* d_in, const int* in_sizes, int n_in,
                              void* d_out, int out_size, void* d_ws, size_t ws_size,
                              hipStream_t stream) {
    const float* x    = (const float*)d_in[0];
    const int*   edges= (const int*)d_in[1];
    const int*   pair = (const int*)d_in[2];
    const float* encW = (const float*)d_in[3];
    const float* encb = (const float*)d_in[4];
    const float* Wl   = (const float*)d_in[5];
    const float* bl   = (const float*)d_in[6];
    const float* Wr   = (const float*)d_in[7];
    const float* W1   = (const float*)d_in[8];
    const float* b1   = (const float*)d_in[9];
    const float* W2   = (const float*)d_in[10];
    const float* b2   = (const float*)d_in[11];
    float* out = (float*)d_out;

    const int N = N_NODES_C, E = N_EDGES_C, P = N_PAIRS_C;
    const int* dst = edges + E;
    const int M = NBKT * NB_S;

    char* w = (char*)d_ws;
    auto alloc = [&](size_t bytes) { char* p = w; w += (bytes + 255) & ~(size_t)255; return p; };
    int*   rowptr = (int*)alloc((size_t)(N + 1) * 4);
    int*   histT  = (int*)alloc((size_t)M * 4);
    int*   offs   = (int*)alloc((size_t)M * 4);
    int*   bsums  = (int*)alloc(128 * 4);
    float* invd   = (float*)alloc((size_t)N * 4);
    int*   adj    = (int*)alloc((size_t)E * 4);
    float* h0     = (float*)alloc((size_t)N * HID_C * 4);
    float* h1     = (float*)alloc((size_t)N * HID_C * 4);
    float* agg    = (float*)alloc((size_t)N * HID_C * 4);
    __half* h16a  = (__half*)alloc((size_t)N * HID_C * 2);
    __half* h16b  = (__half*)alloc((size_t)N * HID_C * 2);
    int2*  staging= (int2*)agg;

    int nscan = (M + SCAN_ELEMS - 1) / SCAN_ELEMS;

    hipLaunchKernelGGL(k_hist, dim3(NB_S), dim3(256), 0, stream, dst, histT, E);
    hipLaunchKernelGGL(k_scan_partial, dim3(nscan), dim3(SCAN_TPB), 0, stream, histT, offs, bsums, M);
    hipLaunchKernelGGL(k_scan_blocks, dim3(1), dim3(128), 0, stream, bsums, nscan);
    hipLaunchKernelGGL(k_scan_addg, dim3((M + 255) / 256), dim3(256), 0, stream, offs, bsums, M);
    hipLaunchKernelGGL(k_scatter, dim3(NB_S), dim3(256), 0, stream, edges, offs, staging, E);
    hipLaunchKernelGGL(k_bucket_fill, dim3(NBKT), dim3(256), 0, stream, staging, offs, rowptr, invd, adj, N, E);

    const int NB128 = (N + 127) / 128;

    k_nn<0><<<dim3(NB128), dim3(256), 0, stream>>>(
        x, nullptr, encW, nullptr, encb, h0, h16a, N);

    float* hc = h0; float* hn = h1;
    __half* h16c = h16a; __half* h16n = h16b;
    for (int l = 0; l < 3; l++) {
        // 2 nodes per wave -> grid covers N/2 wave-pairs, 4 waves/block
        hipLaunchKernelGGL(k_aggregate, dim3((N / 2 + 3) / 4), dim3(256), 0, stream,
                           rowptr, adj, invd, h16c, agg, N);
        // layer 2 (l==2) output never feeds another aggregate: skip fp16 mirror
        k_nn<1><<<dim3(NB128), dim3(256), 0, stream>>>(
            agg, hc, Wl + (size_t)l * 64 * 64, Wr + (size_t)l * 64 * 64,
            bl + (size_t)l * 64, hn, (l < 2) ? h16n : (__half*)nullptr, N);
        float* tswap = hc; hc = hn; hn = tswap;
        __half* t16 = h16c; h16c = h16n; h16n = t16;
    }

    // pred path: UV = h @ [W1_top | W1_bot], then per-pair gather-reduce.
    // U reuses agg (staging long dead), V reuses the retired h buffer (hn).
    float* Ubuf = agg;
    float* Vbuf = hn;
    const int NB_UV = (N + 127) / 128;
    hipLaunchKernelGGL(k_uv, dim3(NB_UV), dim3(256), 0, stream, hc, W1, Ubuf, Vbuf, N);
    hipLaunchKernelGGL(k_pred, dim3((P + 15) / 16), dim3(256), 0, stream,
                       Ubuf, Vbuf, pair, b1, W2, b2, out, P);
}

// Round 9
// 341.211 us; speedup vs baseline: 2.0334x; 1.2002x over previous
//
#include <hip/hip_runtime.h>
#include <hip/hip_fp16.h>
#include <cstdint>
#include <cstddef>

#define N_NODES_C 100000
#define N_EDGES_C 1250000
#define N_PAIRS_C 200000
#define IN_DIM_C 128
#define HID_C 64

// graph-build geometry
#define NB_S 256
#define BSH 9
#define NPB 512
#define NBKT 196
#define SEG_CAP 8192

typedef _Float16 f16x8 __attribute__((ext_vector_type(8)));
typedef float f32x4 __attribute__((ext_vector_type(4)));

// ---------------- scan helpers ----------------

#define SCAN_TPB 256
#define SCAN_IPT 4
#define SCAN_ELEMS 1024

__global__ void k_scan_partial(const int* __restrict__ in, int* __restrict__ outp,
                               int* __restrict__ blocksums, int n) {
    __shared__ int sd[SCAN_TPB];
    int tid = threadIdx.x;
    int base = blockIdx.x * SCAN_ELEMS + tid * SCAN_IPT;
    int v[SCAN_IPT]; int s = 0;
    for (int k = 0; k < SCAN_IPT; k++) { int idx = base + k; v[k] = (idx < n) ? in[idx] : 0; s += v[k]; }
    sd[tid] = s;
    __syncthreads();
    for (int off = 1; off < SCAN_TPB; off <<= 1) {
        int t = (tid >= off) ? sd[tid - off] : 0;
        __syncthreads();
        sd[tid] += t;
        __syncthreads();
    }
    int excl = sd[tid] - s;
    for (int k = 0; k < SCAN_IPT; k++) { int idx = base + k; if (idx < n) outp[idx] = excl; excl += v[k]; }
    if (tid == SCAN_TPB - 1) blocksums[blockIdx.x] = sd[tid];
}

__global__ void k_scan_blocks(int* __restrict__ bs, int nb) {
    __shared__ int sd[128];
    int t = threadIdx.x;
    int v = (t < nb) ? bs[t] : 0;
    sd[t] = v;
    __syncthreads();
    for (int off = 1; off < 128; off <<= 1) {
        int u = (t >= off) ? sd[t - off] : 0;
        __syncthreads();
        sd[t] += u;
        __syncthreads();
    }
    if (t < nb) bs[t] = sd[t] - v;
}

__global__ void k_scan_addg(int* __restrict__ arr, const int* __restrict__ bs, int n) {
    int i = blockIdx.x * blockDim.x + threadIdx.x;
    if (i < n) arr[i] += bs[i >> 10];
}

// ---------------- graph build: two-level counting sort ----------------

__global__ __launch_bounds__(256) void k_hist(const int* __restrict__ dst,
                                              int* __restrict__ histT, int e) {
    __shared__ int lh[NBKT];
    int tid = threadIdx.x, k = blockIdx.x;
    if (tid < NBKT) lh[tid] = 0;
    __syncthreads();
    int chunk = (e + NB_S - 1) / NB_S;
    int i0 = k * chunk, i1 = min(i0 + chunk, e);
    for (int i = i0 + tid; i < i1; i += 256) atomicAdd(&lh[dst[i] >> BSH], 1);
    __syncthreads();
    if (tid < NBKT) histT[tid * NB_S + k] = lh[tid];
}

__global__ __launch_bounds__(256) void k_scatter(const int* __restrict__ edges,
                                                 const int* __restrict__ offs,
                                                 int2* __restrict__ staging, int e) {
    __shared__ int cur[NBKT];
    int tid = threadIdx.x, k = blockIdx.x;
    if (tid < NBKT) cur[tid] = offs[tid * NB_S + k];
    __syncthreads();
    int chunk = (e + NB_S - 1) / NB_S;
    int i0 = k * chunk, i1 = min(i0 + chunk, e);
    for (int i = i0 + tid; i < i1; i += 256) {
        int s = edges[i];
        int d = edges[e + i];
        int p = atomicAdd(&cur[d >> BSH], 1);
        staging[p] = make_int2(s, d);
    }
}

__global__ __launch_bounds__(256) void k_bucket_fill(const int2* __restrict__ staging,
        const int* __restrict__ offs, int* __restrict__ rowptr,
        float* __restrict__ invd, int* __restrict__ adj, int n, int e) {
    __shared__ int ldeg[NPB];
    __shared__ int lrow[NPB];
    __shared__ int ps[256];
    __shared__ int lseg[SEG_CAP];
    int tid = threadIdx.x, b = blockIdx.x;
    int n0 = b << BSH;
    int nn = min(NPB, n - n0);
    int segBeg = offs[b * NB_S];
    int segEnd = (b == NBKT - 1) ? e : offs[(b + 1) * NB_S];

    ldeg[tid] = 0; ldeg[tid + 256] = 0;
    __syncthreads();
    for (int i = segBeg + tid; i < segEnd; i += 256)
        atomicAdd(&ldeg[staging[i].y - n0], 1);
    __syncthreads();

    int a0 = ldeg[2 * tid], a1 = ldeg[2 * tid + 1];
    int s = a0 + a1;
    ps[tid] = s;
    __syncthreads();
    for (int off = 1; off < 256; off <<= 1) {
        int t = (tid >= off) ? ps[tid - off] : 0;
        __syncthreads();
        ps[tid] += t;
        __syncthreads();
    }
    int excl = ps[tid] - s;
    lrow[2 * tid] = excl;
    lrow[2 * tid + 1] = excl + a0;
    __syncthreads();

    for (int j = tid; j < nn; j += 256) {
        rowptr[n0 + j] = segBeg + lrow[j];
        int d = ldeg[j];
        invd[n0 + j] = (d > 0) ? (1.0f / (float)d) : 0.0f;
    }
    if (b == NBKT - 1 && tid == 0) rowptr[n] = e;
    __syncthreads();

    for (int i = segBeg + tid; i < segEnd; i += 256) {
        int2 ed = staging[i];
        int p = atomicAdd(&lrow[ed.y - n0], 1);
        if (p < SEG_CAP) lseg[p] = ed.x;
        else adj[segBeg + p] = ed.x;
    }
    __syncthreads();

    int m = segEnd - segBeg; if (m > SEG_CAP) m = SEG_CAP;
    for (int p = tid; p < m; p += 256) adj[segBeg + p] = lseg[p];
}

// ---------------- aggregation ----------------
// fp16-gather, TWO NODES PER WAVE (R8 win: 50->36 us). Lanes 0-31 = node A,
// lanes 32-63 = node B; each lane owns 2 cols via __half2. NEW this round:
// writes fp16 agg directly (feeds the MFMA GEMM; saves half the write BW).
// History: R4 fusion 3.2x worse (concurrency-bound); R5 instruction shave
// neutral (was memory-bound); R7 fp16 gather -8%; R8 2-nodes/wave -20%.

__global__ __launch_bounds__(256) void k_aggregate(const int* __restrict__ rowptr,
        const int* __restrict__ adj, const float* __restrict__ invd,
        const __half* __restrict__ hin16, __half* __restrict__ agg16, int n) {
    int wid = threadIdx.x >> 6, lane = threadIdx.x & 63;
    int nodeA = (blockIdx.x * 4 + wid) * 2;
    if (nodeA >= n) return;
    const int half_ = lane >> 5;       // 0: node A, 1: node B
    const int c2 = (lane & 31) * 2;    // columns c2, c2+1
    int node = nodeA + half_;
    bool valid = node < n;
    int nodec = valid ? node : n - 1;
    int beg = rowptr[nodec], end = rowptr[nodec + 1];
    float accx = 0.f, accy = 0.f;
    for (int e = beg; e < end; e += 8) {
        int idx[8];
        #pragma unroll
        for (int j = 0; j < 8; ++j) {
            int ee = e + j;
            idx[j] = adj[ee < end ? ee : end - 1];
        }
        __half2 v[8];
        #pragma unroll
        for (int j = 0; j < 8; ++j)
            v[j] = *(const __half2*)&hin16[(size_t)idx[j] * HID_C + c2];
        #pragma unroll
        for (int j = 0; j < 8; ++j) {
            float2 f = __half22float2(v[j]);
            bool in = (e + j < end);
            accx += in ? f.x : 0.f;
            accy += in ? f.y : 0.f;
        }
    }
    if (valid) {
        float s = invd[node];
        *(__half2*)&agg16[(size_t)node * HID_C + c2] =
            __floats2half2_rn(accx * s, accy * s);
    }
}

// ---------------- helpers ----------------

__device__ __forceinline__ float4 ld4(const float* p) { return *(const float4*)p; }

__device__ __forceinline__ void fma4(float4& acc, float sc, const float4& wv) {
    acc.x = fmaf(sc, wv.x, acc.x);
    acc.y = fmaf(sc, wv.y, acc.y);
    acc.z = fmaf(sc, wv.z, acc.z);
    acc.w = fmaf(sc, wv.w, acc.w);
}

// ---------------- k_mm: MFMA fp16 GEMM (enc + layers) ------------------------
// out = relu(A @ W + b), K=128, BM=128 x BN=64 per block, 4 waves, each wave
// 32 rows x 64 cols = 2x4 frags of 16x16, K as 4 steps of
// mfma_f32_16x16x32_f16 (fp16 in, f32 accumulate). LDS: Ah[128][128] fp16
// 32 KB + Bt[64][128] fp16 16 KB = 48 KB -> 3 blocks/CU.
// k-octet XOR swizzle (o ^ (row&15)) on both store and read -> 2-way banks
// (free, m136). A and B staged with the SAME assumed k-per-lane map
// (k=(l>>4)*8+j), so any true HW k-permutation cancels in the dot product;
// C/D layout is the HW-verified col=lane&15, row=(lane>>4)*4+reg.
// SRC 0: A = x (f32, stride 128, converted in staging), W = Ws1 (128x64)
// SRC 1: A = [agg16 | h16] (fp16, stride 64 each), W = [Ws1;Ws2] (64x64 each)

template<int SRC>
__global__ __launch_bounds__(256, 2) void k_mm(
    const float* __restrict__ A1f,
    const __half* __restrict__ A1h, const __half* __restrict__ A2h,
    const float* __restrict__ Ws1, const float* __restrict__ Ws2,
    const float* __restrict__ bias,
    float* __restrict__ outp, __half* __restrict__ out16, int nrows)
{
    __shared__ __half Ah[128 * 128];  // [row][k-swizzled], 32 KB
    __shared__ __half Bt[64 * 128];   // [col][k-swizzled], 16 KB
    const int t = threadIdx.x;
    const int g0 = blockIdx.x * 128;

    // stage A: 128 rows x 16 k-octets (octet = 8 halves = 16 B)
    #pragma unroll
    for (int p = 0; p < 8; ++p) {
        int li = p * 256 + t;
        int r = li >> 4;              // 0..127
        int o = li & 15;              // octet
        int g = g0 + r; if (g > nrows - 1) g = nrows - 1;
        f16x8 v;
        if (SRC == 0) {
            const float* src = A1f + (size_t)g * 128 + o * 8;
            float4 f0 = ld4(src), f1 = ld4(src + 4);
            v[0] = (_Float16)f0.x; v[1] = (_Float16)f0.y;
            v[2] = (_Float16)f0.z; v[3] = (_Float16)f0.w;
            v[4] = (_Float16)f1.x; v[5] = (_Float16)f1.y;
            v[6] = (_Float16)f1.z; v[7] = (_Float16)f1.w;
        } else {
            const __half* src = (o < 8) ? (A1h + (size_t)g * 64 + o * 8)
                                        : (A2h + (size_t)g * 64 + (o - 8) * 8);
            v = *(const f16x8*)src;
        }
        *(f16x8*)&Ah[r * 128 + (o ^ (r & 15)) * 8] = v;
    }
    // stage Bt[c][k] = W[k][c] in fp16 (transpose + convert; weights L2-hot)
    #pragma unroll
    for (int p = 0; p < 32; ++p) {
        int li = p * 256 + t;
        int c = li & 63;
        int k = li >> 6;              // 0..127
        float wv;
        if (SRC == 0) wv = Ws1[k * 64 + c];
        else          wv = (k < 64) ? Ws1[k * 64 + c] : Ws2[(k - 64) * 64 + c];
        Bt[c * 128 + (((k >> 3) ^ (c & 15)) * 8) + (k & 7)] = __float2half(wv);
    }
    __syncthreads();

    const int lane = t & 63;
    const int wid = t >> 6;
    const int R = wid * 32;           // wave's 32-row strip
    const int lr = lane & 15;
    const int lk = lane >> 4;         // octet-within-K-step

    f32x4 acc[2][4];
    #pragma unroll
    for (int fr = 0; fr < 2; ++fr)
        #pragma unroll
        for (int fc = 0; fc < 4; ++fc)
            acc[fr][fc] = (f32x4){0.f, 0.f, 0.f, 0.f};

    #pragma unroll
    for (int ks = 0; ks < 4; ++ks) {
        int o = ks * 4 + lk;          // octet 0..15
        f16x8 af0, af1;
        {
            int r0 = R + lr;
            int r1 = R + 16 + lr;
            af0 = *(const f16x8*)&Ah[r0 * 128 + (o ^ (r0 & 15)) * 8];
            af1 = *(const f16x8*)&Ah[r1 * 128 + (o ^ (r1 & 15)) * 8];
        }
        #pragma unroll
        for (int fc = 0; fc < 4; ++fc) {
            int c = fc * 16 + lr;
            f16x8 bf = *(const f16x8*)&Bt[c * 128 + (o ^ (c & 15)) * 8];
            acc[0][fc] = __builtin_amdgcn_mfma_f32_16x16x32_f16(af0, bf, acc[0][fc], 0, 0, 0);
            acc[1][fc] = __builtin_amdgcn_mfma_f32_16x16x32_f16(af1, bf, acc[1][fc], 0, 0, 0);
        }
    }

    // epilogue: C[row=(lane>>4)*4+j][col=lane&15] per 16x16 frag (HW-verified)
    float bv[4];
    #pragma unroll
    for (int fc = 0; fc < 4; ++fc) bv[fc] = bias[fc * 16 + lr];
    #pragma unroll
    for (int fr = 0; fr < 2; ++fr) {
        #pragma unroll
        for (int j = 0; j < 4; ++j) {
            int gr = g0 + R + fr * 16 + lk * 4 + j;
            if (gr < nrows) {
                #pragma unroll
                for (int fc = 0; fc < 4; ++fc) {
                    int col = fc * 16 + lr;
                    float v = fmaxf(acc[fr][fc][j] + bv[fc], 0.f);
                    outp[(size_t)gr * 64 + col] = v;
                    if (out16) out16[(size_t)gr * 64 + col] = __float2half(v);
                }
            }
        }
    }
}

// ---------------- pred-path factorization ----------------
// z@W1 = (h@W1[:64])[a] + (h@W1[64:])[b].
// k_uv: UV GEMM, M=100k K=64 N=128 (U cols 0..63, V cols 64..127), 8x8 thread
// tile, f32 throughout (pred-path precision preserved). XOR swizzle
// sw=(k>>2)*4.

__global__ __launch_bounds__(256, 2) void k_uv(
    const float* __restrict__ H, const float* __restrict__ W1,
    float* __restrict__ U, float* __restrict__ V, int nrows)
{
    __shared__ float AT[64 * 128];   // [k][row^sw], 32 KB
    __shared__ float Wm[64 * 128];   // [k][col],    32 KB
    const int t = threadIdx.x;
    const int g0 = blockIdx.x * 128;

    #pragma unroll
    for (int p = 0; p < 8; ++p) {
        int li = p * 256 + t;          // 0..2047
        int k = li >> 5;               // 0..63
        int j4 = (li & 31) * 4;        // 0..124
        float4 wv = (j4 < 64) ? ld4(W1 + k * 64 + j4)
                              : ld4(W1 + (64 + k) * 64 + (j4 - 64));
        *(float4*)&Wm[k * 128 + j4] = wv;
    }
    #pragma unroll
    for (int p = 0; p < 8; ++p) {
        int li = p * 256 + t;          // 128 rows x 16 col4-groups
        int r = li >> 4;               // 0..127
        int c4 = (li & 15) * 4;        // 0..60
        int g = g0 + r; if (g > nrows - 1) g = nrows - 1;
        float4 av = ld4(H + (size_t)g * 64 + c4);
        AT[(c4    ) * 128 + (r ^ (((c4    ) >> 2) * 4))] = av.x;
        AT[(c4 + 1) * 128 + (r ^ (((c4 + 1) >> 2) * 4))] = av.y;
        AT[(c4 + 2) * 128 + (r ^ (((c4 + 2) >> 2) * 4))] = av.z;
        AT[(c4 + 3) * 128 + (r ^ (((c4 + 3) >> 2) * 4))] = av.w;
    }
    __syncthreads();

    const int tc = t & 15, tr = t >> 4;
    const int c0 = tc * 4;             // U cols c0..c0+3, V cols 64+c0..+3
    const int r0 = tr * 8;             // rows r0..r0+7
    float4 accA[8], accB[8];
    #pragma unroll
    for (int i = 0; i < 8; ++i) {
        accA[i] = make_float4(0.f, 0.f, 0.f, 0.f);
        accB[i] = make_float4(0.f, 0.f, 0.f, 0.f);
    }

    #pragma unroll 4
    for (int k = 0; k < 64; ++k) {
        const float* arow = &AT[k * 128];
        int sw = (k >> 2) * 4;
        float4 a0 = ld4(arow + ((r0    ) ^ sw));   // rows r0..r0+3 at this k
        float4 a1 = ld4(arow + ((r0 + 4) ^ sw));   // rows r0+4..r0+7
        float4 w0 = ld4(&Wm[k * 128 + c0]);        // U cols
        float4 w1 = ld4(&Wm[k * 128 + 64 + c0]);   // V cols
        fma4(accA[0], a0.x, w0); fma4(accB[0], a0.x, w1);
        fma4(accA[1], a0.y, w0); fma4(accB[1], a0.y, w1);
        fma4(accA[2], a0.z, w0); fma4(accB[2], a0.z, w1);
        fma4(accA[3], a0.w, w0); fma4(accB[3], a0.w, w1);
        fma4(accA[4], a1.x, w0); fma4(accB[4], a1.x, w1);
        fma4(accA[5], a1.y, w0); fma4(accB[5], a1.y, w1);
        fma4(accA[6], a1.z, w0); fma4(accB[6], a1.z, w1);
        fma4(accA[7], a1.w, w0); fma4(accB[7], a1.w, w1);
    }

    #pragma unroll
    for (int i = 0; i < 8; ++i) {
        int g = g0 + r0 + i;
        if (g < nrows) {
            *(float4*)&U[(size_t)g * 64 + c0] = accA[i];
            *(float4*)&V[(size_t)g * 64 + c0] = accB[i];
        }
    }
}

// k_pred: out[p] = relu(U[a] + V[b] + b1) . W2 + b2 — pure gather-reduce.
// 16 lanes per pair, 256 B coalesced row per gather, shfl-reduce width 16.
__global__ __launch_bounds__(256) void k_pred(
    const float* __restrict__ U, const float* __restrict__ V,
    const int* __restrict__ pidx, const float* __restrict__ b1,
    const float* __restrict__ W2, const float* __restrict__ b2,
    float* __restrict__ outp, int np)
{
    const int t = threadIdx.x;
    const int lg = t & 15;
    const int p = blockIdx.x * 16 + (t >> 4);
    float4 bv = ld4(b1 + lg * 4);
    float4 wv = ld4(W2 + lg * 4);
    if (p >= np) return;
    int2 ab = ((const int2*)pidx)[p];
    float4 u = ld4(U + (size_t)ab.x * 64 + lg * 4);
    float4 v = ld4(V + (size_t)ab.y * 64 + lg * 4);
    float zx = fmaxf(u.x + v.x + bv.x, 0.f);
    float zy = fmaxf(u.y + v.y + bv.y, 0.f);
    float zz = fmaxf(u.z + v.z + bv.z, 0.f);
    float zw = fmaxf(u.w + v.w + bv.w, 0.f);
    float s = zx * wv.x + zy * wv.y + zz * wv.z + zw * wv.w;
    s += __shfl_down(s, 8, 16);
    s += __shfl_down(s, 4, 16);
    s += __shfl_down(s, 2, 16);
    s += __shfl_down(s, 1, 16);
    if (lg == 0) outp[p] = s + b2[0];
}

// ---------------- launch ----------------

extern "C" void kernel_launch(void* const* d_in, const int* in_sizes, int n_in,
                              void* d_out, int out_size, void* d_ws, size_t ws_size,
                              hipStream_t stream) {
    const float* x    = (const float*)d_in[0];
    const int*   edges= (const int*)d_in[1];
    const int*   pair = (const int*)d_in[2];
    const float* encW = (const float*)d_in[3];
    const float* encb = (const float*)d_in[4];
    const float* Wl   = (const float*)d_in[5];
    const float* bl   = (const float*)d_in[6];
    const float* Wr   = (const float*)d_in[7];
    const float* W1   = (const float*)d_in[8];
    const float* b1   = (const float*)d_in[9];
    const float* W2   = (const float*)d_in[10];
    const float* b2   = (const float*)d_in[11];
    float* out = (float*)d_out;

    const int N = N_NODES_C, E = N_EDGES_C, P = N_PAIRS_C;
    const int* dst = edges + E;
    const int M = NBKT * NB_S;

    char* w = (char*)d_ws;
    auto alloc = [&](size_t bytes) { char* p = w; w += (bytes + 255) & ~(size_t)255; return p; };
    int*   rowptr = (int*)alloc((size_t)(N + 1) * 4);
    int*   histT  = (int*)alloc((size_t)M * 4);
    int*   offs   = (int*)alloc((size_t)M * 4);
    int*   bsums  = (int*)alloc(128 * 4);
    float* invd   = (float*)alloc((size_t)N * 4);
    int*   adj    = (int*)alloc((size_t)E * 4);
    float* h0     = (float*)alloc((size_t)N * HID_C * 4);
    float* h1     = (float*)alloc((size_t)N * HID_C * 4);
    float* agg    = (float*)alloc((size_t)N * HID_C * 4);
    __half* h16a  = (__half*)alloc((size_t)N * HID_C * 2);
    __half* h16b  = (__half*)alloc((size_t)N * HID_C * 2);
    __half* agg16 = (__half*)alloc((size_t)N * HID_C * 2);
    int2*  staging= (int2*)agg;

    int nscan = (M + SCAN_ELEMS - 1) / SCAN_ELEMS;

    hipLaunchKernelGGL(k_hist, dim3(NB_S), dim3(256), 0, stream, dst, histT, E);
    hipLaunchKernelGGL(k_scan_partial, dim3(nscan), dim3(SCAN_TPB), 0, stream, histT, offs, bsums, M);
    hipLaunchKernelGGL(k_scan_blocks, dim3(1), dim3(128), 0, stream, bsums, nscan);
    hipLaunchKernelGGL(k_scan_addg, dim3((M + 255) / 256), dim3(256), 0, stream, offs, bsums, M);
    hipLaunchKernelGGL(k_scatter, dim3(NB_S), dim3(256), 0, stream, edges, offs, staging, E);
    hipLaunchKernelGGL(k_bucket_fill, dim3(NBKT), dim3(256), 0, stream, staging, offs, rowptr, invd, adj, N, E);

    const int NB128 = (N + 127) / 128;

    // encoder: MFMA fp16 (x converted in staging)
    k_mm<0><<<dim3(NB128), dim3(256), 0, stream>>>(
        x, nullptr, nullptr, encW, nullptr, encb, h0, h16a, N);

    float* hc = h0; float* hn = h1;
    __half* h16c = h16a; __half* h16n = h16b;
    for (int l = 0; l < 3; l++) {
        hipLaunchKernelGGL(k_aggregate, dim3((N / 2 + 3) / 4), dim3(256), 0, stream,
                           rowptr, adj, invd, h16c, agg16, N);
        // layer 2 (l==2) output never feeds another aggregate: skip fp16 mirror
        k_mm<1><<<dim3(NB128), dim3(256), 0, stream>>>(
            nullptr, agg16, h16c, Wl + (size_t)l * 64 * 64, Wr + (size_t)l * 64 * 64,
            bl + (size_t)l * 64, hn, (l < 2) ? h16n : (__half*)nullptr, N);
        float* tswap = hc; hc = hn; hn = tswap;
        __half* t16 = h16c; h16c = h16n; h16n = t16;
    }

    // pred path (f32): UV = h @ [W1_top | W1_bot], then per-pair gather-reduce.
    float* Ubuf = agg;
    float* Vbuf = hn;
    const int NB_UV = (N + 127) / 128;
    hipLaunchKernelGGL(k_uv, dim3(NB_UV), dim3(256), 0, stream, hc, W1, Ubuf, Vbuf, N);
    hipLaunchKernelGGL(k_pred, dim3((P + 15) / 16), dim3(256), 0, stream,
                       Ubuf, Vbuf, pair, b1, W2, b2, out, P);
}